// Round 11
// baseline (189.037 us; speedup 1.0000x reference)
//
#include <hip/hip_runtime.h>
#include <stdint.h>

/* AdditiveAttention (B=4, Q=256, K=1024, D=512, H=256)
 * out[b,i,v] = sum_j softmax_j(sum_h tanh(q[b,i,h]+k[b,j,h])*wv[h]) * values[b,j,v],
 * masked to j < valid_lens[b].  OUTPUT IS FLOAT32 (R20 finding).
 *
 * R31: P1 memory-side restructure. R10 cut VALU-busy 56->37us (factored exp,
 * pair-rcp) but duration only 96->85: ~48us of latency stall exposed. P1 was
 * issuing 256 scalar b32 kp loads/thread (4KB h-stride) at VGPR=36 — tiny
 * ILP window on ~250cy L2 latency. Fix: kp stored INTERLEAVED kp4[b][j][k]
 * (float4 = 4 consecutive h at one k) -> 64 b128 loads/thread (4x fewer
 * instrs, same coalescing); qs stored [row][h] so Aq = 1 b128 broadcast per
 * row per j. Pair-rcp math identical to R10 (verified). ff_proj writes kp4
 * via 4KB LDS transpose (reuses xs). Structure else unchanged
 * (K-split attn2 + comb; proj 5 blk/CU; wt). */

#define NB 4
#define NQ 256
#define NK 1024
#define ND 512
#define NH 256
#define QROWS 4
#define PJR 16
#define PJH 64

#define C2L2E 2.8853900817779268f   /* 2*log2(e) */
#define L2E   1.4426950408889634f   /* log2(e)   */

typedef float v2f __attribute__((ext_vector_type(2)));

/* 8-class valid_lens decode: {i32,i64,f32,f64,i16,f16,bf16,fallback}. */
__device__ void ff_vldec(const int* p, int* v) {
  bool ok = true;
  for (int i = 0; i < 4; ++i) { int x = p[i]; if (x < 1 || x > NK) ok = false; }
  if (ok) { for (int i = 0; i < 4; ++i) v[i] = p[i]; return; }
  ok = true;
  for (int i = 0; i < 4; ++i) {
    if (p[2 * i + 1] != 0) ok = false;
    int x = p[2 * i]; if (x < 1 || x > NK) ok = false;
  }
  if (ok) { for (int i = 0; i < 4; ++i) v[i] = p[2 * i]; return; }
  ok = true;
  for (int i = 0; i < 4; ++i) {
    union { int i; float f; } u; u.i = p[i];
    if (!(u.f >= 1.0f && u.f <= 1024.0f && u.f == floorf(u.f))) ok = false;
  }
  if (ok) {
    for (int i = 0; i < 4; ++i) { union { int i; float f; } u; u.i = p[i]; v[i] = (int)u.f; }
    return;
  }
  ok = true;
  for (int i = 0; i < 4; ++i) {
    union { long long l; double d; } u;
    u.l = ((long long)p[2 * i + 1] << 32) | (unsigned int)p[2 * i];
    if (!(u.d >= 1.0 && u.d <= 1024.0 && u.d == floor(u.d))) ok = false;
  }
  if (ok) {
    for (int i = 0; i < 4; ++i) {
      union { long long l; double d; } u;
      u.l = ((long long)p[2 * i + 1] << 32) | (unsigned int)p[2 * i];
      v[i] = (int)u.d;
    }
    return;
  }
  const uint16_t* hh = (const uint16_t*)p;
  const short*    s  = (const short*)p;
  ok = true;
  for (int i = 0; i < 4; ++i) { int x = s[i]; if (x < 1 || x > NK) ok = false; }
  if (ok) { for (int i = 0; i < 4; ++i) v[i] = s[i]; return; }
  ok = true;
  for (int i = 0; i < 4; ++i) {
    union { uint16_t u; _Float16 h; } u; u.u = hh[i];
    float f = (float)u.h;
    if (!(f >= 1.0f && f <= 1024.0f && f == floorf(f))) ok = false;
  }
  if (ok) {
    for (int i = 0; i < 4; ++i) {
      union { uint16_t u; _Float16 h; } u; u.u = hh[i];
      v[i] = (int)(float)u.h;
    }
    return;
  }
  ok = true;
  for (int i = 0; i < 4; ++i) {
    union { uint32_t u; float f; } u; u.u = ((uint32_t)hh[i]) << 16;
    if (!(u.f >= 1.0f && u.f <= 1028.0f)) ok = false;
  }
  if (ok) {
    for (int i = 0; i < 4; ++i) {
      union { uint32_t u; float f; } u; u.u = ((uint32_t)hh[i]) << 16;
      int x = (int)(u.f + 0.5f); if (x > NK) x = NK; v[i] = x;
    }
    return;
  }
  for (int i = 0; i < 4; ++i) v[i] = NK;  /* fail-safe: unmasked */
}

/* Transpose W[h][d] -> WT float4 #(d4*NH+h) = C2L2E * W[h][4d4..4d4+3]. */
__global__ __launch_bounds__(256) void ff_wt(
    const float* __restrict__ Wq, const float* __restrict__ Wk,
    float* __restrict__ WTq, float* __restrict__ WTk)
{
  const int idx = blockIdx.x * 256 + threadIdx.x;   /* 0..32767 */
  const int d4 = idx & 127, h = idx >> 7;
  const float* src = blockIdx.y ? Wk : Wq;
  float*       dst = blockIdx.y ? WTk : WTq;
  float4 w = *(const float4*)(src + (size_t)h * ND + d4 * 4);
  w.x *= C2L2E; w.y *= C2L2E; w.z *= C2L2E; w.w *= C2L2E;
  *(float4*)(dst + ((size_t)d4 * NH + h) * 4) = w;
}

/* Projection (R7 grid, 5 blk/CU): outputs Aq=2^{q'} (qp [r][h]) and
 * Ak=2^{k'} in INTERLEAVED kp4[b][j][k] (float4 of h=4j..4j+3 at one k),
 * written via a 4KB LDS transpose reusing xs. */
__global__ __launch_bounds__(256) void ff_proj(
    const float* __restrict__ q_in, const float* __restrict__ k_in,
    const float* __restrict__ WTq, const float* __restrict__ WTk,
    float* __restrict__ qp, float* __restrict__ kp)
{
  __shared__ float xs[PJR * ND];                 /* 32 KB */
  const int t  = threadIdx.x;
  const int rg = blockIdx.x >> 2;                /* 0..319 */
  const int h0 = (blockIdx.x & 3) * PJH;
  const int gr0 = rg * PJR;
  const bool isq = gr0 < NB * NQ;
  const float* xin = isq ? (q_in + (size_t)gr0 * ND)
                         : (k_in + (size_t)(gr0 - NB * NQ) * ND);
  const float4* wt4 = (const float4*)(isq ? WTq : WTk);

  #pragma unroll
  for (int i = 0; i < 8; ++i)
    ((float4*)xs)[t + 256 * i] = ((const float4*)xin)[t + 256 * i];
  __syncthreads();

  const int L  = t & 63;
  const int rw = t >> 6;
  float a0 = 0.f, a1 = 0.f, a2 = 0.f, a3 = 0.f;
  const float4* xr = (const float4*)xs + (size_t)(4 * rw) * 128;

  #pragma unroll 4
  for (int d4 = 0; d4 < ND / 4; ++d4) {
    float4 w  = wt4[(size_t)d4 * NH + h0 + L];
    float4 x0 = xr[d4];
    float4 x1 = xr[128 + d4];
    float4 x2 = xr[256 + d4];
    float4 x3 = xr[384 + d4];
    a0 += w.x*x0.x + w.y*x0.y + w.z*x0.z + w.w*x0.w;
    a1 += w.x*x1.x + w.y*x1.y + w.z*x1.z + w.w*x1.w;
    a2 += w.x*x2.x + w.y*x2.y + w.z*x2.z + w.w*x2.w;
    a3 += w.x*x3.x + w.y*x3.y + w.z*x3.z + w.w*x3.w;
  }
  a0 = __builtin_amdgcn_exp2f(a0);
  a1 = __builtin_amdgcn_exp2f(a1);
  a2 = __builtin_amdgcn_exp2f(a2);
  a3 = __builtin_amdgcn_exp2f(a3);

  if (isq) {
    const int h = h0 + L;
    float* o = qp + (size_t)(gr0 + 4 * rw) * NH + h;
    o[0] = a0; o[NH] = a1; o[2 * NH] = a2; o[3 * NH] = a3;
  } else {
    /* transpose (h-lane, 4k) -> (k-lane, 4h) through LDS, write kp4 */
    __syncthreads();                         /* xs reads done */
    float* trs = xs;                         /* [64 h][16 k] */
    *(float4*)&trs[L * 16 + 4 * rw] = make_float4(a0, a1, a2, a3);
    __syncthreads();
    const int kl = t & 15, jl = t >> 4;      /* jl 0..15 */
    const int g0 = gr0 - NB * NQ;
    const int bb = g0 >> 10, kg0 = g0 & (NK - 1);
    const int j0 = (blockIdx.x & 3) * 16;
    float4 o4 = make_float4(trs[(4*jl+0)*16 + kl], trs[(4*jl+1)*16 + kl],
                            trs[(4*jl+2)*16 + kl], trs[(4*jl+3)*16 + kl]);
    ((float4*)kp)[((size_t)bb * 64 + j0 + jl) * 1024 + kg0 + kl] = o4;
  }
}

/* K-split attention half (R10 structure; R31 P1 memory-side).
 * P1 per j (4 h): 1 b128 kp4 load + 2 b128 qs broadcasts + 2 b128 wspp +
 * 2x pair-rcp math (R10-verified).  E unnormalized; S_half -> Sg.
 * P3: split-k PV -> pvpart. */
__global__ __launch_bounds__(1024) void ff_attn2(
    const float* __restrict__ qp, const float* __restrict__ kp,
    const float* __restrict__ vals, const int* __restrict__ vlraw,
    const float* __restrict__ wvp, float* __restrict__ pvpart,
    float* __restrict__ Sg)
{
  __shared__ float  qs[QROWS * NH];       /* Aq [row][h]               4 KB */
  __shared__ float4 wspp[NH / 2];         /* pair p: (-2w0,-2w1,-2(w0+w1),0) 2KB */
  __shared__ float  st[512 * QROWS];      /* [k_local][row] E          8 KB */
  __shared__ float  psum[32];
  __shared__ float  part[4 * QROWS * ND]; /* split-k partials         32 KB */

  const int t  = threadIdx.x;
  const int kh = blockIdx.x;              /* k half */
  const int q0 = blockIdx.y * QROWS;
  const int b  = blockIdx.z;

  {
    const float* qsrc = qp + ((size_t)b * NQ + q0) * NH;
    qs[t] = qsrc[t];                      /* [row][h] == linear */
    if (t < NH / 2) {
      float w0 = wvp[2 * t], w1 = wvp[2 * t + 1];
      wspp[t] = make_float4(-2.0f * w0, -2.0f * w1, -2.0f * (w0 + w1), 0.0f);
    }
  }
  __syncthreads();

  int vls[4];
  ff_vldec(vlraw, vls);
  const int vl = vls[b];

  /* ---- P1: scores -> E, 2 rows per thread, j = 4-h groups ---- */
  const int kk = t & 511, rh = t >> 9;
  v2f acc = {0.f, 0.f};
  {
    const float4* kvp = (const float4*)kp + ((size_t)b * 64) * 1024
                      + (kh * 512 + kk);
    const float* q0p = qs + (2 * rh) * NH;
    const float* q1p = qs + (2 * rh + 1) * NH;
    #pragma unroll 4
    for (int j = 0; j < 64; ++j) {
      float4 K4 = kvp[(size_t)j << 10];
      float4 A0 = *(const float4*)(q0p + 4 * j);
      float4 A1 = *(const float4*)(q1p + 4 * j);
      float4 wa = wspp[2 * j];
      float4 wb = wspp[2 * j + 1];
      v2f one; one.x = 1.0f; one.y = 1.0f;
      {                                    /* pair 0: h = 4j, 4j+1 */
        v2f a;  a.x  = A0.x * K4.x; a.y  = A1.x * K4.x;
        v2f b2; b2.x = A0.y * K4.y; b2.y = A1.y * K4.y;
        v2f D = (one + a) * (one + b2);
        v2f N;   N.x = wa.z;  N.y = wa.z;
        v2f w0v; w0v.x = wa.x; w0v.y = wa.x;
        v2f w1v; w1v.x = wa.y; w1v.y = wa.y;
        N += w0v * b2;
        N += w1v * a;
        v2f rD;
        rD.x = __builtin_amdgcn_rcpf(D.x);
        rD.y = __builtin_amdgcn_rcpf(D.y);
        acc += N * rD;
      }
      {                                    /* pair 1: h = 4j+2, 4j+3 */
        v2f a;  a.x  = A0.z * K4.z; a.y  = A1.z * K4.z;
        v2f b2; b2.x = A0.w * K4.w; b2.y = A1.w * K4.w;
        v2f D = (one + a) * (one + b2);
        v2f N;   N.x = wb.z;  N.y = wb.z;
        v2f w0v; w0v.x = wb.x; w0v.y = wb.x;
        v2f w1v; w1v.x = wb.y; w1v.y = wb.y;
        N += w0v * b2;
        N += w1v * a;
        v2f rD;
        rD.x = __builtin_amdgcn_rcpf(D.x);
        rD.y = __builtin_amdgcn_rcpf(D.y);
        acc += N * rD;
      }
    }
  }
  {
    const bool okm = (kh * 512 + kk) < vl;
    v2f E;
    E.x = okm ? __builtin_amdgcn_exp2f(acc.x * L2E) : 0.f;
    E.y = okm ? __builtin_amdgcn_exp2f(acc.y * L2E) : 0.f;
    *(v2f*)&st[kk * 4 + 2 * rh] = E;
    float sx = E.x, sy = E.y;
    for (int o = 32; o; o >>= 1) { sx += __shfl_xor(sx, o); sy += __shfl_xor(sy, o); }
    if ((t & 63) == 0) { psum[(t >> 6) * 2] = sx; psum[(t >> 6) * 2 + 1] = sy; }
  }
  __syncthreads();

  if (t < 4) {                            /* row r: waves (r>>1)*8.., slot r&1 */
    const int j = t & 1, base = (t >> 1) * 8;
    float S = 0.f;
    #pragma unroll
    for (int w = 0; w < 8; ++w) S += psum[(base + w) * 2 + j];
    Sg[(((size_t)b * 64 + blockIdx.y) * 4 + t) * 2 + kh] = S;
  }

  /* ---- P3: PV over this half, 4 quarters of 128 k ---- */
  {
    const int kq = t >> 8, c2 = (t & 255) * 2;
    const float* vb = vals + (size_t)b * NK * ND
                    + (size_t)(kh * 512 + kq * 128) * ND + c2;
    v2f o0 = {0.f,0.f}, o1 = {0.f,0.f}, o2 = {0.f,0.f}, o3 = {0.f,0.f};
    #pragma unroll 8
    for (int k = 0; k < 128; ++k) {
      v2f vv = *(const v2f*)(vb + (size_t)k * ND);
      float4 a = *(const float4*)&st[(kq * 128 + k) * 4];
      v2f ax; ax.x = a.x; ax.y = a.x;
      v2f ay; ay.x = a.y; ay.y = a.y;
      v2f az; az.x = a.z; az.y = a.z;
      v2f aw; aw.x = a.w; aw.y = a.w;
      o0 += ax * vv; o1 += ay * vv; o2 += az * vv; o3 += aw * vv;
    }
    *(v2f*)&part[(size_t)(kq * 4 + 0) * ND + c2] = o0;
    *(v2f*)&part[(size_t)(kq * 4 + 1) * ND + c2] = o1;
    *(v2f*)&part[(size_t)(kq * 4 + 2) * ND + c2] = o2;
    *(v2f*)&part[(size_t)(kq * 4 + 3) * ND + c2] = o3;
  }
  __syncthreads();
  {
    const int r = t >> 8, c2 = (t & 255) * 2;
    v2f s = {0.f, 0.f};
    #pragma unroll
    for (int kq = 0; kq < 4; ++kq)
      s += *(const v2f*)&part[(size_t)(kq * 4 + r) * ND + c2];
    *(v2f*)&pvpart[(((size_t)kh * NB + b) * NQ + q0 + r) * ND + c2] = s;
  }
}

/* Combine: out = (PV0+PV1)/(S0+S1).  1024 blocks x 256 thr. */
__global__ __launch_bounds__(256) void ff_comb(
    const float* __restrict__ pvpart, const float* __restrict__ Sg,
    float* __restrict__ out)
{
  const int bid = blockIdx.x;             /* b*256 + q */
  const int t = threadIdx.x;
  const float S = Sg[bid * 2] + Sg[bid * 2 + 1];
  const float rs = 1.0f / S;
  const int b = bid >> 8, q = bid & 255;
  const float* p0 = pvpart + ((size_t)b * NQ + q) * ND;
  const float* p1 = pvpart + ((size_t)(NB + b) * NQ + q) * ND;
  float2 a = *(const float2*)(p0 + t * 2);
  float2 c = *(const float2*)(p1 + t * 2);
  *(float2*)(out + ((size_t)b * NQ + q) * ND + t * 2)
      = make_float2((a.x + c.x) * rs, (a.y + c.y) * rs);
}

/* Fallback attn (kp4 inputs, full K, in-kernel max-softmax) for small ws. */
__global__ __launch_bounds__(1024) void ff_attn(
    const float* __restrict__ qp, const float* __restrict__ kp,
    const float* __restrict__ vals, const int* __restrict__ vlraw,
    const float* __restrict__ wvp, float* __restrict__ out)
{
  __shared__ float qs[QROWS * NH];        /* [row][h] */
  __shared__ float ws[NH];
  __shared__ float st[NK * QROWS];
  __shared__ float pm[16], psm[16];
  __shared__ float part[4 * QROWS * ND];

  const int t  = threadIdx.x;
  const int q0 = blockIdx.x * QROWS;
  const int b  = blockIdx.y;

  {
    const float* qsrc = qp + ((size_t)b * NQ + q0) * NH;
    qs[t] = qsrc[t];
    if (t < NH) ws[t] = -2.0f * wvp[t];
  }
  __syncthreads();

  int vls[4];
  ff_vldec(vlraw, vls);
  const int vl = vls[b];

  float sc[4] = {0.f, 0.f, 0.f, 0.f};
  {
    const float4* kvp = (const float4*)kp + ((size_t)b * 64) * 1024 + t;
    for (int j = 0; j < 64; ++j) {
      float4 K4 = kvp[(size_t)j << 10];
      const float* wj = &ws[4 * j];
      #pragma unroll
      for (int r = 0; r < 4; ++r) {
        const float* qr = &qs[r * NH + 4 * j];
        sc[r] += wj[0] * __builtin_amdgcn_rcpf(1.0f + qr[0] * K4.x);
        sc[r] += wj[1] * __builtin_amdgcn_rcpf(1.0f + qr[1] * K4.y);
        sc[r] += wj[2] * __builtin_amdgcn_rcpf(1.0f + qr[2] * K4.z);
        sc[r] += wj[3] * __builtin_amdgcn_rcpf(1.0f + qr[3] * K4.w);
      }
    }
  }
  {
    const bool okm = (t < vl);
    *(float4*)&st[t * 4] = make_float4(okm ? sc[0] : -1e6f, okm ? sc[1] : -1e6f,
                                       okm ? sc[2] : -1e6f, okm ? sc[3] : -1e6f);
  }
  __syncthreads();

  {
    const int wid = t >> 6, lane = t & 63;
    const int row = wid >> 2, seg = wid & 3;
    const int kb = seg * 256 + lane;
    float v0 = st[(kb      ) * 4 + row];
    float v1 = st[(kb +  64) * 4 + row];
    float v2 = st[(kb + 128) * 4 + row];
    float v3 = st[(kb + 192) * 4 + row];
    float m = fmaxf(fmaxf(v0, v1), fmaxf(v2, v3));
    for (int o = 32; o; o >>= 1) m = fmaxf(m, __shfl_xor(m, o));
    if (lane == 0) pm[wid] = m;
    __syncthreads();
    m = fmaxf(fmaxf(pm[row*4+0], pm[row*4+1]), fmaxf(pm[row*4+2], pm[row*4+3]));
    float e0 = __builtin_amdgcn_exp2f((v0 - m) * L2E);
    float e1 = __builtin_amdgcn_exp2f((v1 - m) * L2E);
    float e2 = __builtin_amdgcn_exp2f((v2 - m) * L2E);
    float e3 = __builtin_amdgcn_exp2f((v3 - m) * L2E);
    float sm = e0 + e1 + e2 + e3;
    for (int o = 32; o; o >>= 1) sm += __shfl_xor(sm, o);
    if (lane == 0) psm[wid] = sm;
    __syncthreads();
    const float S = psm[row*4+0] + psm[row*4+1] + psm[row*4+2] + psm[row*4+3];
    const float rr = 1.0f / S;
    st[(kb      ) * 4 + row] = e0 * rr;
    st[(kb +  64) * 4 + row] = e1 * rr;
    st[(kb + 128) * 4 + row] = e2 * rr;
    st[(kb + 192) * 4 + row] = e3 * rr;
  }
  __syncthreads();

  {
    const int kq = t >> 8, c2 = (t & 255) * 2;
    const float* vb = vals + (size_t)b * NK * ND + c2;
    v2f o0 = {0.f,0.f}, o1 = {0.f,0.f}, o2 = {0.f,0.f}, o3 = {0.f,0.f};
    const int k0 = kq * 256;
    #pragma unroll 8
    for (int k = k0; k < k0 + 256; ++k) {
      v2f vv = *(const v2f*)(vb + (size_t)k * ND);
      float4 a = *(const float4*)&st[k * 4];
      v2f ax; ax.x = a.x; ax.y = a.x;
      v2f ay; ay.x = a.y; ay.y = a.y;
      v2f az; az.x = a.z; az.y = a.z;
      v2f aw; aw.x = a.w; aw.y = a.w;
      o0 += ax * vv; o1 += ay * vv; o2 += az * vv; o3 += aw * vv;
    }
    float* pp = &part[(size_t)kq * QROWS * ND + c2];
    *(v2f*)(pp         ) = o0;
    *(v2f*)(pp +     ND) = o1;
    *(v2f*)(pp + 2 * ND) = o2;
    *(v2f*)(pp + 3 * ND) = o3;
  }
  __syncthreads();
  {
    const int r = t >> 8, c2 = (t & 255) * 2;
    const float* pp = &part[(size_t)r * ND + c2];
    v2f s = {0.f, 0.f};
    #pragma unroll
    for (int kq = 0; kq < 4; ++kq) s += *(const v2f*)(pp + (size_t)kq * QROWS * ND);
    *(v2f*)(out + ((size_t)b * NQ + q0 + r) * ND + c2) = s;
  }
}

extern "C" void kernel_launch(void* const* d_in, const int* in_sizes, int n_in,
                              void* d_out, int out_size, void* d_ws, size_t ws_size,
                              hipStream_t stream) {
  const float* queries = (const float*)d_in[0];
  const float* keys    = (const float*)d_in[1];
  const float* values  = (const float*)d_in[2];
  const int*   vlens   = (const int*)d_in[3];
  const float* Wq      = (const float*)d_in[4];
  const float* Wk      = (const float*)d_in[5];
  const float* wv      = (const float*)d_in[6];
  float* out = (float*)d_out;               /* F32 OUTPUT */

  float* qp  = (float*)d_ws;                    /* 1 MB  */
  float* kp  = qp  + (size_t)NB * NQ * NH;      /* 4 MB (kp4 layout) */
  float* wtq = kp  + (size_t)NB * NH * NK;      /* 512 KB */
  float* wtk = wtq + (size_t)(ND / 4) * NH * 4; /* 512 KB */
  float* pvp = wtk + (size_t)(ND / 4) * NH * 4; /* 4 MB  */
  float* Sg  = pvp + (size_t)2 * NB * NQ * ND;  /* 8 KB  */
  const size_t need = ((size_t)(Sg - (float*)d_ws) + 2 * NB * NQ) * sizeof(float);

  ff_wt  <<<dim3(128, 2), 256, 0, stream>>>(Wq, Wk, wtq, wtk);
  ff_proj<<<dim3((NB * (NQ + NK) / PJR) * (NH / PJH)), 256, 0, stream>>>(
      queries, keys, wtq, wtk, qp, kp);
  if (ws_size >= need) {
    ff_attn2<<<dim3(2, NQ / QROWS, NB), 1024, 0, stream>>>(
        qp, kp, values, vlens, wv, pvp, Sg);
    ff_comb<<<dim3(NB * NQ), 256, 0, stream>>>(pvp, Sg, out);
  } else {
    ff_attn<<<dim3(NQ / QROWS, NB), 1024, 0, stream>>>(
        qp, kp, values, vlens, wv, out);
  }
}

// Round 12
// 187.132 us; speedup vs baseline: 1.0102x; 1.0102x over previous
//
#include <hip/hip_runtime.h>
#include <stdint.h>

/* AdditiveAttention (B=4, Q=256, K=1024, D=512, H=256)
 * out[b,i,v] = sum_j softmax_j(sum_h tanh(q[b,i,h]+k[b,j,h])*wv[h]) * values[b,j,v],
 * masked to j < valid_lens[b].  OUTPUT IS FLOAT32 (R20 finding).
 *
 * R32: residency/granularity. R10/R11 proved attn2 isn't bound by VALU,
 * trans, or VMEM instr count (each fixed, ~2us moved). Occupancy stuck at
 * 42% = ONE resident block (grid 512 = exactly 2/CU -> staggered serial
 * pairs + long tail). Fix: K split into 4 chunks of 256 (grid 1024), LDS
 * cut to ~30KB (part 16KB via 2 sub-halves; stp partial-score buf reused
 * for E) -> 4-5 blocks/CU capacity, fully co-resident, tail/4, P1/P3
 * phases overlap across blocks. 1024 thr absorb an h-split (each thread
 * sums 32 of 64 j-groups; halves combined in LDS pre-exp2) — pair-rcp math
 * identical to R10/R11 (verified). comb sums 4 partials. proj/wt unchanged. */

#define NB 4
#define NQ 256
#define NK 1024
#define ND 512
#define NH 256
#define QROWS 4
#define PJR 16
#define PJH 64

#define C2L2E 2.8853900817779268f   /* 2*log2(e) */
#define L2E   1.4426950408889634f   /* log2(e)   */

typedef float v2f __attribute__((ext_vector_type(2)));

/* 8-class valid_lens decode: {i32,i64,f32,f64,i16,f16,bf16,fallback}. */
__device__ void ff_vldec(const int* p, int* v) {
  bool ok = true;
  for (int i = 0; i < 4; ++i) { int x = p[i]; if (x < 1 || x > NK) ok = false; }
  if (ok) { for (int i = 0; i < 4; ++i) v[i] = p[i]; return; }
  ok = true;
  for (int i = 0; i < 4; ++i) {
    if (p[2 * i + 1] != 0) ok = false;
    int x = p[2 * i]; if (x < 1 || x > NK) ok = false;
  }
  if (ok) { for (int i = 0; i < 4; ++i) v[i] = p[2 * i]; return; }
  ok = true;
  for (int i = 0; i < 4; ++i) {
    union { int i; float f; } u; u.i = p[i];
    if (!(u.f >= 1.0f && u.f <= 1024.0f && u.f == floorf(u.f))) ok = false;
  }
  if (ok) {
    for (int i = 0; i < 4; ++i) { union { int i; float f; } u; u.i = p[i]; v[i] = (int)u.f; }
    return;
  }
  ok = true;
  for (int i = 0; i < 4; ++i) {
    union { long long l; double d; } u;
    u.l = ((long long)p[2 * i + 1] << 32) | (unsigned int)p[2 * i];
    if (!(u.d >= 1.0 && u.d <= 1024.0 && u.d == floor(u.d))) ok = false;
  }
  if (ok) {
    for (int i = 0; i < 4; ++i) {
      union { long long l; double d; } u;
      u.l = ((long long)p[2 * i + 1] << 32) | (unsigned int)p[2 * i];
      v[i] = (int)u.d;
    }
    return;
  }
  const uint16_t* hh = (const uint16_t*)p;
  const short*    s  = (const short*)p;
  ok = true;
  for (int i = 0; i < 4; ++i) { int x = s[i]; if (x < 1 || x > NK) ok = false; }
  if (ok) { for (int i = 0; i < 4; ++i) v[i] = s[i]; return; }
  ok = true;
  for (int i = 0; i < 4; ++i) {
    union { uint16_t u; _Float16 h; } u; u.u = hh[i];
    float f = (float)u.h;
    if (!(f >= 1.0f && f <= 1024.0f && f == floorf(f))) ok = false;
  }
  if (ok) {
    for (int i = 0; i < 4; ++i) {
      union { uint16_t u; _Float16 h; } u; u.u = hh[i];
      v[i] = (int)(float)u.h;
    }
    return;
  }
  ok = true;
  for (int i = 0; i < 4; ++i) {
    union { uint32_t u; float f; } u; u.u = ((uint32_t)hh[i]) << 16;
    if (!(u.f >= 1.0f && u.f <= 1028.0f)) ok = false;
  }
  if (ok) {
    for (int i = 0; i < 4; ++i) {
      union { uint32_t u; float f; } u; u.u = ((uint32_t)hh[i]) << 16;
      int x = (int)(u.f + 0.5f); if (x > NK) x = NK; v[i] = x;
    }
    return;
  }
  for (int i = 0; i < 4; ++i) v[i] = NK;  /* fail-safe: unmasked */
}

/* Transpose W[h][d] -> WT float4 #(d4*NH+h) = C2L2E * W[h][4d4..4d4+3]. */
__global__ __launch_bounds__(256) void ff_wt(
    const float* __restrict__ Wq, const float* __restrict__ Wk,
    float* __restrict__ WTq, float* __restrict__ WTk)
{
  const int idx = blockIdx.x * 256 + threadIdx.x;   /* 0..32767 */
  const int d4 = idx & 127, h = idx >> 7;
  const float* src = blockIdx.y ? Wk : Wq;
  float*       dst = blockIdx.y ? WTk : WTq;
  float4 w = *(const float4*)(src + (size_t)h * ND + d4 * 4);
  w.x *= C2L2E; w.y *= C2L2E; w.z *= C2L2E; w.w *= C2L2E;
  *(float4*)(dst + ((size_t)d4 * NH + h) * 4) = w;
}

/* Projection (R11, proven): Aq=2^{q'} (qp [r][h]); Ak=2^{k'} interleaved
 * kp4[b][j][k] (float4 = h 4j..4j+3 at one k) via 4KB LDS transpose. */
__global__ __launch_bounds__(256) void ff_proj(
    const float* __restrict__ q_in, const float* __restrict__ k_in,
    const float* __restrict__ WTq, const float* __restrict__ WTk,
    float* __restrict__ qp, float* __restrict__ kp)
{
  __shared__ float xs[PJR * ND];                 /* 32 KB */
  const int t  = threadIdx.x;
  const int rg = blockIdx.x >> 2;                /* 0..319 */
  const int h0 = (blockIdx.x & 3) * PJH;
  const int gr0 = rg * PJR;
  const bool isq = gr0 < NB * NQ;
  const float* xin = isq ? (q_in + (size_t)gr0 * ND)
                         : (k_in + (size_t)(gr0 - NB * NQ) * ND);
  const float4* wt4 = (const float4*)(isq ? WTq : WTk);

  #pragma unroll
  for (int i = 0; i < 8; ++i)
    ((float4*)xs)[t + 256 * i] = ((const float4*)xin)[t + 256 * i];
  __syncthreads();

  const int L  = t & 63;
  const int rw = t >> 6;
  float a0 = 0.f, a1 = 0.f, a2 = 0.f, a3 = 0.f;
  const float4* xr = (const float4*)xs + (size_t)(4 * rw) * 128;

  #pragma unroll 4
  for (int d4 = 0; d4 < ND / 4; ++d4) {
    float4 w  = wt4[(size_t)d4 * NH + h0 + L];
    float4 x0 = xr[d4];
    float4 x1 = xr[128 + d4];
    float4 x2 = xr[256 + d4];
    float4 x3 = xr[384 + d4];
    a0 += w.x*x0.x + w.y*x0.y + w.z*x0.z + w.w*x0.w;
    a1 += w.x*x1.x + w.y*x1.y + w.z*x1.z + w.w*x1.w;
    a2 += w.x*x2.x + w.y*x2.y + w.z*x2.z + w.w*x2.w;
    a3 += w.x*x3.x + w.y*x3.y + w.z*x3.z + w.w*x3.w;
  }
  a0 = __builtin_amdgcn_exp2f(a0);
  a1 = __builtin_amdgcn_exp2f(a1);
  a2 = __builtin_amdgcn_exp2f(a2);
  a3 = __builtin_amdgcn_exp2f(a3);

  if (isq) {
    const int h = h0 + L;
    float* o = qp + (size_t)(gr0 + 4 * rw) * NH + h;
    o[0] = a0; o[NH] = a1; o[2 * NH] = a2; o[3 * NH] = a3;
  } else {
    __syncthreads();                         /* xs reads done */
    float* trs = xs;                         /* [64 h][16 k] */
    *(float4*)&trs[L * 16 + 4 * rw] = make_float4(a0, a1, a2, a3);
    __syncthreads();
    const int kl = t & 15, jl = t >> 4;      /* jl 0..15 */
    const int g0 = gr0 - NB * NQ;
    const int bb = g0 >> 10, kg0 = g0 & (NK - 1);
    const int j0 = (blockIdx.x & 3) * 16;
    float4 o4 = make_float4(trs[(4*jl+0)*16 + kl], trs[(4*jl+1)*16 + kl],
                            trs[(4*jl+2)*16 + kl], trs[(4*jl+3)*16 + kl]);
    ((float4*)kp)[((size_t)bb * 64 + j0 + jl) * 1024 + kg0 + kl] = o4;
  }
}

/* 4-way K-split attention chunk: grid (4, 64, 4) = 1024 blocks, 1024 thr,
 * ~30KB LDS -> 4+ blocks/CU co-resident.  Thread: kk=t&255, row-pair
 * rh=(t>>8)&1, h-half hs=t>>9 (j in [32hs,32hs+32)).  Pair-rcp math
 * identical to R10/R11 (verified).  Partial scores combined in LDS, E
 * unnormalized; S_chunk -> Sg; P3 PV over 256 k -> pvpart. */
__global__ __launch_bounds__(1024) void ff_attn4(
    const float* __restrict__ qp, const float* __restrict__ kp,
    const float* __restrict__ vals, const int* __restrict__ vlraw,
    const float* __restrict__ wvp, float* __restrict__ pvpart,
    float* __restrict__ Sg)
{
  __shared__ float  qs[QROWS * NH];       /* Aq [row][h]               4 KB */
  __shared__ float4 wspp[NH / 2];         /* (-2w0,-2w1,-2(w0+w1),0)   2 KB */
  __shared__ float  stp[2 * 256 * 4];     /* [hs][k][row] partials->E  8 KB */
  __shared__ float  psum[16];
  __shared__ float  part[2 * 4 * 512];    /* [kq][row][c]             16 KB */

  const int t  = threadIdx.x;
  const int ck = blockIdx.x;              /* k chunk 0..3 */
  const int q0 = blockIdx.y * QROWS;
  const int b  = blockIdx.z;

  {
    qs[t] = qp[((size_t)b * NQ + q0) * NH + t];   /* [row][h] linear */
    if (t < NH / 2) {
      float w0 = wvp[2 * t], w1 = wvp[2 * t + 1];
      wspp[t] = make_float4(-2.0f * w0, -2.0f * w1, -2.0f * (w0 + w1), 0.0f);
    }
  }
  __syncthreads();

  int vls[4];
  ff_vldec(vlraw, vls);
  const int vl = vls[b];

  /* ---- P1: partial scores, 2 rows/thread, half the h range ---- */
  const int kk = t & 255, rh = (t >> 8) & 1, hs = t >> 9;
  v2f acc = {0.f, 0.f};
  {
    const float4* kvp = (const float4*)kp + ((size_t)b * 64) * 1024
                      + (ck * 256 + kk);
    const float* q0p = qs + (2 * rh) * NH;
    const float* q1p = qs + (2 * rh + 1) * NH;
    #pragma unroll 4
    for (int jj = 0; jj < 32; ++jj) {
      const int j = hs * 32 + jj;
      float4 K4 = kvp[(size_t)j << 10];
      float4 A0 = *(const float4*)(q0p + 4 * j);
      float4 A1 = *(const float4*)(q1p + 4 * j);
      float4 wa = wspp[2 * j];
      float4 wb = wspp[2 * j + 1];
      v2f one; one.x = 1.0f; one.y = 1.0f;
      {                                    /* pair 0: h = 4j, 4j+1 */
        v2f a;  a.x  = A0.x * K4.x; a.y  = A1.x * K4.x;
        v2f b2; b2.x = A0.y * K4.y; b2.y = A1.y * K4.y;
        v2f D = (one + a) * (one + b2);
        v2f N;   N.x = wa.z;  N.y = wa.z;
        v2f w0v; w0v.x = wa.x; w0v.y = wa.x;
        v2f w1v; w1v.x = wa.y; w1v.y = wa.y;
        N += w0v * b2;
        N += w1v * a;
        v2f rD;
        rD.x = __builtin_amdgcn_rcpf(D.x);
        rD.y = __builtin_amdgcn_rcpf(D.y);
        acc += N * rD;
      }
      {                                    /* pair 1: h = 4j+2, 4j+3 */
        v2f a;  a.x  = A0.z * K4.z; a.y  = A1.z * K4.z;
        v2f b2; b2.x = A0.w * K4.w; b2.y = A1.w * K4.w;
        v2f D = (one + a) * (one + b2);
        v2f N;   N.x = wb.z;  N.y = wb.z;
        v2f w0v; w0v.x = wb.x; w0v.y = wb.x;
        v2f w1v; w1v.x = wb.y; w1v.y = wb.y;
        N += w0v * b2;
        N += w1v * a;
        v2f rD;
        rD.x = __builtin_amdgcn_rcpf(D.x);
        rD.y = __builtin_amdgcn_rcpf(D.y);
        acc += N * rD;
      }
    }
  }
  *(v2f*)&stp[(hs * 256 + kk) * 4 + 2 * rh] = acc;
  __syncthreads();

  /* ---- combine h-halves, E = exp2(score'), row-sum ---- */
  {
    const int k = t & 255, row = t >> 8;  /* row 0..3 */
    float s = stp[k * 4 + row] + stp[(256 + k) * 4 + row];
    const bool okm = (ck * 256 + k) < vl;
    float E = okm ? __builtin_amdgcn_exp2f(s * L2E) : 0.f;
    stp[k * 4 + row] = E;                 /* self-slot overwrite, no hazard */
    float sx = E;
    for (int o = 32; o; o >>= 1) sx += __shfl_xor(sx, o);
    if ((t & 63) == 0) psum[t >> 6] = sx; /* wave = row*4 + seg */
  }
  __syncthreads();
  if (t < 4) {
    float S = psum[t * 4] + psum[t * 4 + 1] + psum[t * 4 + 2] + psum[t * 4 + 3];
    Sg[((((size_t)b * 64 + blockIdx.y) * 4 + t)) * 4 + ck] = S;
  }

  /* ---- P3: PV over chunk, 2 sub-halves of 128 k, 1 col/thread ---- */
  {
    const int c = t & 511, kq = t >> 9;
    const float* vb = vals + (size_t)b * NK * ND
                    + (size_t)(ck * 256 + kq * 128) * ND + c;
    float o0 = 0.f, o1 = 0.f, o2 = 0.f, o3 = 0.f;
    #pragma unroll 8
    for (int k = 0; k < 128; ++k) {
      float v = vb[(size_t)k * ND];
      float4 a = *(const float4*)&stp[(kq * 128 + k) * 4];
      o0 += a.x * v; o1 += a.y * v; o2 += a.z * v; o3 += a.w * v;
    }
    part[(kq * 4 + 0) * 512 + c] = o0;
    part[(kq * 4 + 1) * 512 + c] = o1;
    part[(kq * 4 + 2) * 512 + c] = o2;
    part[(kq * 4 + 3) * 512 + c] = o3;
  }
  __syncthreads();
  {
    const int c = t & 511, rp = t >> 9;
    #pragma unroll
    for (int rr = 0; rr < 2; ++rr) {
      const int r = rp * 2 + rr;
      float s = part[(0 * 4 + r) * 512 + c] + part[(1 * 4 + r) * 512 + c];
      pvpart[((size_t)(ck * NB + b) * NQ + q0 + r) * ND + c] = s;
    }
  }
}

/* Combine: out = (PV0+..+PV3)/(S0+..+S3).  1024 blocks x 256 thr. */
__global__ __launch_bounds__(256) void ff_comb(
    const float* __restrict__ pvpart, const float* __restrict__ Sg,
    float* __restrict__ out)
{
  const int bid = blockIdx.x;             /* b*256 + q */
  const int t = threadIdx.x;
  const float* sg = Sg + (size_t)bid * 4;
  const float S = (sg[0] + sg[1]) + (sg[2] + sg[3]);
  const float rs = 1.0f / S;
  const int b = bid >> 8, q = bid & 255;
  float2 acc = make_float2(0.f, 0.f);
  #pragma unroll
  for (int c = 0; c < 4; ++c) {
    const float* p = pvpart + ((size_t)(c * NB + b) * NQ + q) * ND;
    float2 v = *(const float2*)(p + t * 2);
    acc.x += v.x; acc.y += v.y;
  }
  *(float2*)(out + ((size_t)b * NQ + q) * ND + t * 2)
      = make_float2(acc.x * rs, acc.y * rs);
}

/* Fallback attn (kp4 inputs, full K, in-kernel max-softmax) for small ws. */
__global__ __launch_bounds__(1024) void ff_attn(
    const float* __restrict__ qp, const float* __restrict__ kp,
    const float* __restrict__ vals, const int* __restrict__ vlraw,
    const float* __restrict__ wvp, float* __restrict__ out)
{
  __shared__ float qs[QROWS * NH];        /* [row][h] */
  __shared__ float ws[NH];
  __shared__ float st[NK * QROWS];
  __shared__ float pm[16], psm[16];
  __shared__ float part[4 * QROWS * ND];

  const int t  = threadIdx.x;
  const int q0 = blockIdx.x * QROWS;
  const int b  = blockIdx.y;

  {
    const float* qsrc = qp + ((size_t)b * NQ + q0) * NH;
    qs[t] = qsrc[t];
    if (t < NH) ws[t] = -2.0f * wvp[t];
  }
  __syncthreads();

  int vls[4];
  ff_vldec(vlraw, vls);
  const int vl = vls[b];

  float sc[4] = {0.f, 0.f, 0.f, 0.f};
  {
    const float4* kvp = (const float4*)kp + ((size_t)b * 64) * 1024 + t;
    for (int j = 0; j < 64; ++j) {
      float4 K4 = kvp[(size_t)j << 10];
      const float* wj = &ws[4 * j];
      #pragma unroll
      for (int r = 0; r < 4; ++r) {
        const float* qr = &qs[r * NH + 4 * j];
        sc[r] += wj[0] * __builtin_amdgcn_rcpf(1.0f + qr[0] * K4.x);
        sc[r] += wj[1] * __builtin_amdgcn_rcpf(1.0f + qr[1] * K4.y);
        sc[r] += wj[2] * __builtin_amdgcn_rcpf(1.0f + qr[2] * K4.z);
        sc[r] += wj[3] * __builtin_amdgcn_rcpf(1.0f + qr[3] * K4.w);
      }
    }
  }
  {
    const bool okm = (t < vl);
    *(float4*)&st[t * 4] = make_float4(okm ? sc[0] : -1e6f, okm ? sc[1] : -1e6f,
                                       okm ? sc[2] : -1e6f, okm ? sc[3] : -1e6f);
  }
  __syncthreads();

  {
    const int wid = t >> 6, lane = t & 63;
    const int row = wid >> 2, seg = wid & 3;
    const int kb = seg * 256 + lane;
    float v0 = st[(kb      ) * 4 + row];
    float v1 = st[(kb +  64) * 4 + row];
    float v2 = st[(kb + 128) * 4 + row];
    float v3 = st[(kb + 192) * 4 + row];
    float m = fmaxf(fmaxf(v0, v1), fmaxf(v2, v3));
    for (int o = 32; o; o >>= 1) m = fmaxf(m, __shfl_xor(m, o));
    if (lane == 0) pm[wid] = m;
    __syncthreads();
    m = fmaxf(fmaxf(pm[row*4+0], pm[row*4+1]), fmaxf(pm[row*4+2], pm[row*4+3]));
    float e0 = __builtin_amdgcn_exp2f((v0 - m) * L2E);
    float e1 = __builtin_amdgcn_exp2f((v1 - m) * L2E);
    float e2 = __builtin_amdgcn_exp2f((v2 - m) * L2E);
    float e3 = __builtin_amdgcn_exp2f((v3 - m) * L2E);
    float sm = e0 + e1 + e2 + e3;
    for (int o = 32; o; o >>= 1) sm += __shfl_xor(sm, o);
    if (lane == 0) psm[wid] = sm;
    __syncthreads();
    const float S = psm[row*4+0] + psm[row*4+1] + psm[row*4+2] + psm[row*4+3];
    const float rr = 1.0f / S;
    st[(kb      ) * 4 + row] = e0 * rr;
    st[(kb +  64) * 4 + row] = e1 * rr;
    st[(kb + 128) * 4 + row] = e2 * rr;
    st[(kb + 192) * 4 + row] = e3 * rr;
  }
  __syncthreads();

  {
    const int kq = t >> 8, c2 = (t & 255) * 2;
    const float* vb = vals + (size_t)b * NK * ND + c2;
    v2f o0 = {0.f,0.f}, o1 = {0.f,0.f}, o2 = {0.f,0.f}, o3 = {0.f,0.f};
    const int k0 = kq * 256;
    #pragma unroll 8
    for (int k = k0; k < k0 + 256; ++k) {
      v2f vv = *(const v2f*)(vb + (size_t)k * ND);
      float4 a = *(const float4*)&st[k * 4];
      v2f ax; ax.x = a.x; ax.y = a.x;
      v2f ay; ay.x = a.y; ay.y = a.y;
      v2f az; az.x = a.z; az.y = a.z;
      v2f aw; aw.x = a.w; aw.y = a.w;
      o0 += ax * vv; o1 += ay * vv; o2 += az * vv; o3 += aw * vv;
    }
    float* pp = &part[(size_t)kq * QROWS * ND + c2];
    *(v2f*)(pp         ) = o0;
    *(v2f*)(pp +     ND) = o1;
    *(v2f*)(pp + 2 * ND) = o2;
    *(v2f*)(pp + 3 * ND) = o3;
  }
  __syncthreads();
  {
    const int r = t >> 8, c2 = (t & 255) * 2;
    const float* pp = &part[(size_t)r * ND + c2];
    v2f s = {0.f, 0.f};
    #pragma unroll
    for (int kq = 0; kq < 4; ++kq) s += *(const v2f*)(pp + (size_t)kq * QROWS * ND);
    *(v2f*)(out + ((size_t)b * NQ + q0 + r) * ND + c2) = s;
  }
}

extern "C" void kernel_launch(void* const* d_in, const int* in_sizes, int n_in,
                              void* d_out, int out_size, void* d_ws, size_t ws_size,
                              hipStream_t stream) {
  const float* queries = (const float*)d_in[0];
  const float* keys    = (const float*)d_in[1];
  const float* values  = (const float*)d_in[2];
  const int*   vlens   = (const int*)d_in[3];
  const float* Wq      = (const float*)d_in[4];
  const float* Wk      = (const float*)d_in[5];
  const float* wv      = (const float*)d_in[6];
  float* out = (float*)d_out;               /* F32 OUTPUT */

  float* qp  = (float*)d_ws;                    /* 1 MB  */
  float* kp  = qp  + (size_t)NB * NQ * NH;      /* 4 MB (kp4 layout) */
  float* wtq = kp  + (size_t)NB * NH * NK;      /* 512 KB */
  float* wtk = wtq + (size_t)(ND / 4) * NH * 4; /* 512 KB */
  float* pvp = wtk + (size_t)(ND / 4) * NH * 4; /* 8 MB (4 chunks) */
  float* Sg  = pvp + (size_t)4 * NB * NQ * ND;  /* 16 KB */
  const size_t need = ((size_t)(Sg - (float*)d_ws) + 4 * NB * NQ) * sizeof(float);

  ff_wt  <<<dim3(128, 2), 256, 0, stream>>>(Wq, Wk, wtq, wtk);
  ff_proj<<<dim3((NB * (NQ + NK) / PJR) * (NH / PJH)), 256, 0, stream>>>(
      queries, keys, wtq, wtk, qp, kp);
  if (ws_size >= need) {
    ff_attn4<<<dim3(4, NQ / QROWS, NB), 1024, 0, stream>>>(
        qp, kp, values, vlens, wv, pvp, Sg);
    ff_comb<<<dim3(NB * NQ), 256, 0, stream>>>(pvp, Sg, out);
  } else {
    ff_attn<<<dim3(NQ / QROWS, NB), 1024, 0, stream>>>(
        qp, kp, values, vlens, wv, out);
  }
}

// Round 13
// 177.076 us; speedup vs baseline: 1.0675x; 1.0568x over previous
//
#include <hip/hip_runtime.h>
#include <stdint.h>

/* AdditiveAttention (B=4, Q=256, K=1024, D=512, H=256)
 * out[b,i,v] = sum_j softmax_j(sum_h tanh(q[b,i,h]+k[b,j,h])*wv[h]) * values[b,j,v],
 * masked to j < valid_lens[b].  OUTPUT IS FLOAT32 (R20 finding).
 *
 * R33: LDS-pipe elimination. R8-R12 fixed occupancy/VALU/VMEM; duration
 * pinned ~83us. Pipe arithmetic: P1 4 broadcast ds_read_b128/j/thread +
 * P3 1 uniform b128/k/thread = 4.2M wave-instr x 12cyc / 256CU = 82us —
 * the LDS pipe WAS the wall all along. Fix:
 * (a) ff_attn_s: P1 k-register-blocked (thread owns 4 k, 2 rows, h-half;
 *     256 blocks full-K) -> LDS instrs /4 (~10us); E -> global Eg (float4
 *     per k, coalesced) + row-sums Sg. Pair-rcp math = R10-verified.
 * (b) ff_pv: PV reads E via wave-uniform s_load (SMEM pipe, zero LDS in
 *     hot loop); 2048 blocks x 256thr, 8KB LDS, ~8 blk/CU; V-stream
 *     L2-bound ~15us; applies 1/S at the end (ff_comb gone).
 * proj/wt unchanged (R11, kp4 layout). */

#define NB 4
#define NQ 256
#define NK 1024
#define ND 512
#define NH 256
#define QROWS 4
#define PJR 16
#define PJH 64

#define C2L2E 2.8853900817779268f   /* 2*log2(e) */
#define L2E   1.4426950408889634f   /* log2(e)   */

typedef float v2f __attribute__((ext_vector_type(2)));

/* 8-class valid_lens decode: {i32,i64,f32,f64,i16,f16,bf16,fallback}. */
__device__ void ff_vldec(const int* p, int* v) {
  bool ok = true;
  for (int i = 0; i < 4; ++i) { int x = p[i]; if (x < 1 || x > NK) ok = false; }
  if (ok) { for (int i = 0; i < 4; ++i) v[i] = p[i]; return; }
  ok = true;
  for (int i = 0; i < 4; ++i) {
    if (p[2 * i + 1] != 0) ok = false;
    int x = p[2 * i]; if (x < 1 || x > NK) ok = false;
  }
  if (ok) { for (int i = 0; i < 4; ++i) v[i] = p[2 * i]; return; }
  ok = true;
  for (int i = 0; i < 4; ++i) {
    union { int i; float f; } u; u.i = p[i];
    if (!(u.f >= 1.0f && u.f <= 1024.0f && u.f == floorf(u.f))) ok = false;
  }
  if (ok) {
    for (int i = 0; i < 4; ++i) { union { int i; float f; } u; u.i = p[i]; v[i] = (int)u.f; }
    return;
  }
  ok = true;
  for (int i = 0; i < 4; ++i) {
    union { long long l; double d; } u;
    u.l = ((long long)p[2 * i + 1] << 32) | (unsigned int)p[2 * i];
    if (!(u.d >= 1.0 && u.d <= 1024.0 && u.d == floor(u.d))) ok = false;
  }
  if (ok) {
    for (int i = 0; i < 4; ++i) {
      union { long long l; double d; } u;
      u.l = ((long long)p[2 * i + 1] << 32) | (unsigned int)p[2 * i];
      v[i] = (int)u.d;
    }
    return;
  }
  const uint16_t* hh = (const uint16_t*)p;
  const short*    s  = (const short*)p;
  ok = true;
  for (int i = 0; i < 4; ++i) { int x = s[i]; if (x < 1 || x > NK) ok = false; }
  if (ok) { for (int i = 0; i < 4; ++i) v[i] = s[i]; return; }
  ok = true;
  for (int i = 0; i < 4; ++i) {
    union { uint16_t u; _Float16 h; } u; u.u = hh[i];
    float f = (float)u.h;
    if (!(f >= 1.0f && f <= 1024.0f && f == floorf(f))) ok = false;
  }
  if (ok) {
    for (int i = 0; i < 4; ++i) {
      union { uint16_t u; _Float16 h; } u; u.u = hh[i];
      v[i] = (int)(float)u.h;
    }
    return;
  }
  ok = true;
  for (int i = 0; i < 4; ++i) {
    union { uint32_t u; float f; } u; u.u = ((uint32_t)hh[i]) << 16;
    if (!(u.f >= 1.0f && u.f <= 1028.0f)) ok = false;
  }
  if (ok) {
    for (int i = 0; i < 4; ++i) {
      union { uint32_t u; float f; } u; u.u = ((uint32_t)hh[i]) << 16;
      int x = (int)(u.f + 0.5f); if (x > NK) x = NK; v[i] = x;
    }
    return;
  }
  for (int i = 0; i < 4; ++i) v[i] = NK;  /* fail-safe: unmasked */
}

/* Transpose W[h][d] -> WT float4 #(d4*NH+h) = C2L2E * W[h][4d4..4d4+3]. */
__global__ __launch_bounds__(256) void ff_wt(
    const float* __restrict__ Wq, const float* __restrict__ Wk,
    float* __restrict__ WTq, float* __restrict__ WTk)
{
  const int idx = blockIdx.x * 256 + threadIdx.x;   /* 0..32767 */
  const int d4 = idx & 127, h = idx >> 7;
  const float* src = blockIdx.y ? Wk : Wq;
  float*       dst = blockIdx.y ? WTk : WTq;
  float4 w = *(const float4*)(src + (size_t)h * ND + d4 * 4);
  w.x *= C2L2E; w.y *= C2L2E; w.z *= C2L2E; w.w *= C2L2E;
  *(float4*)(dst + ((size_t)d4 * NH + h) * 4) = w;
}

/* Projection (R11, proven): Aq=2^{q'} (qp [r][h]); Ak=2^{k'} interleaved
 * kp4[b][j][k] (float4 = h 4j..4j+3 at one k) via 4KB LDS transpose. */
__global__ __launch_bounds__(256) void ff_proj(
    const float* __restrict__ q_in, const float* __restrict__ k_in,
    const float* __restrict__ WTq, const float* __restrict__ WTk,
    float* __restrict__ qp, float* __restrict__ kp)
{
  __shared__ float xs[PJR * ND];                 /* 32 KB */
  const int t  = threadIdx.x;
  const int rg = blockIdx.x >> 2;                /* 0..319 */
  const int h0 = (blockIdx.x & 3) * PJH;
  const int gr0 = rg * PJR;
  const bool isq = gr0 < NB * NQ;
  const float* xin = isq ? (q_in + (size_t)gr0 * ND)
                         : (k_in + (size_t)(gr0 - NB * NQ) * ND);
  const float4* wt4 = (const float4*)(isq ? WTq : WTk);

  #pragma unroll
  for (int i = 0; i < 8; ++i)
    ((float4*)xs)[t + 256 * i] = ((const float4*)xin)[t + 256 * i];
  __syncthreads();

  const int L  = t & 63;
  const int rw = t >> 6;
  float a0 = 0.f, a1 = 0.f, a2 = 0.f, a3 = 0.f;
  const float4* xr = (const float4*)xs + (size_t)(4 * rw) * 128;

  #pragma unroll 4
  for (int d4 = 0; d4 < ND / 4; ++d4) {
    float4 w  = wt4[(size_t)d4 * NH + h0 + L];
    float4 x0 = xr[d4];
    float4 x1 = xr[128 + d4];
    float4 x2 = xr[256 + d4];
    float4 x3 = xr[384 + d4];
    a0 += w.x*x0.x + w.y*x0.y + w.z*x0.z + w.w*x0.w;
    a1 += w.x*x1.x + w.y*x1.y + w.z*x1.z + w.w*x1.w;
    a2 += w.x*x2.x + w.y*x2.y + w.z*x2.z + w.w*x2.w;
    a3 += w.x*x3.x + w.y*x3.y + w.z*x3.z + w.w*x3.w;
  }
  a0 = __builtin_amdgcn_exp2f(a0);
  a1 = __builtin_amdgcn_exp2f(a1);
  a2 = __builtin_amdgcn_exp2f(a2);
  a3 = __builtin_amdgcn_exp2f(a3);

  if (isq) {
    const int h = h0 + L;
    float* o = qp + (size_t)(gr0 + 4 * rw) * NH + h;
    o[0] = a0; o[NH] = a1; o[2 * NH] = a2; o[3 * NH] = a3;
  } else {
    __syncthreads();                         /* xs reads done */
    float* trs = xs;                         /* [64 h][16 k] */
    *(float4*)&trs[L * 16 + 4 * rw] = make_float4(a0, a1, a2, a3);
    __syncthreads();
    const int kl = t & 15, jl = t >> 4;      /* jl 0..15 */
    const int g0 = gr0 - NB * NQ;
    const int bb = g0 >> 10, kg0 = g0 & (NK - 1);
    const int j0 = (blockIdx.x & 3) * 16;
    float4 o4 = make_float4(trs[(4*jl+0)*16 + kl], trs[(4*jl+1)*16 + kl],
                            trs[(4*jl+2)*16 + kl], trs[(4*jl+3)*16 + kl]);
    ((float4*)kp)[((size_t)bb * 64 + j0 + jl) * 1024 + kg0 + kl] = o4;
  }
}

/* Scores kernel: grid (64 q4, 4 b) = 256 blocks, 1024 thr, full K.
 * Thread: kk=t&255 owns k=4kk..4kk+3; rh=(t>>8)&1 row-pair; hs=t>>9 h-half
 * (j in [32hs,32hs+32)).  Per j: 4 VMEM b128 (kp4) + 4 LDS b128 (Aq x2,
 * wspp x2) amortized over 4 k.  Pair-rcp math = R10-verified.  Partials
 * combined via stride-5 LDS (conflict-free); E=exp2 unnormalized -> Eg
 * (float4/k, coalesced); row sums -> Sg. */
__global__ __launch_bounds__(1024) void ff_attn_s(
    const float* __restrict__ qp, const float* __restrict__ kp,
    const int* __restrict__ vlraw, const float* __restrict__ wvp,
    float* __restrict__ Eg, float* __restrict__ Sg)
{
  __shared__ float  qs[QROWS * NH];       /* Aq [row][h]            4 KB */
  __shared__ float4 wspp[NH / 2];         /* (-2w0,-2w1,-2(w0+w1),0) 2 KB */
  __shared__ float  pstp[2 * NK * 5];     /* [hs][k][5] partials    40 KB */
  __shared__ float  psum[16 * 4];

  const int t  = threadIdx.x;
  const int q4 = blockIdx.x;
  const int b  = blockIdx.y;

  qs[t] = qp[((size_t)b * NQ + q4 * QROWS) * NH + t];
  if (t < NH / 2) {
    float w0 = wvp[2 * t], w1 = wvp[2 * t + 1];
    wspp[t] = make_float4(-2.0f * w0, -2.0f * w1, -2.0f * (w0 + w1), 0.0f);
  }
  __syncthreads();

  int vls[4];
  ff_vldec(vlraw, vls);
  const int vl = vls[b];

  const int kk = t & 255, rh = (t >> 8) & 1, hs = t >> 9;
  const int k0 = kk * 4;

  v2f acc0 = {0.f,0.f}, acc1 = {0.f,0.f}, acc2 = {0.f,0.f}, acc3 = {0.f,0.f};
  {
    const float4* kvp = (const float4*)kp + (size_t)b * 64 * 1024 + k0;
    const float* q0p = qs + (2 * rh) * NH;
    const float* q1p = qs + (2 * rh + 1) * NH;

    #pragma unroll 2
    for (int jj = 0; jj < 32; ++jj) {
      const int j = hs * 32 + jj;
      const float4* kj = kvp + ((size_t)j << 10);
      float4 K0 = kj[0], K1 = kj[1], K2 = kj[2], K3 = kj[3];
      float4 A0 = *(const float4*)(q0p + 4 * j);
      float4 A1 = *(const float4*)(q1p + 4 * j);
      float4 wa = wspp[2 * j];
      float4 wb = wspp[2 * j + 1];
      v2f one; one.x = 1.0f; one.y = 1.0f;

#define FF_PAIRK(K4, ACC)                                                  \
      {                                                                    \
        v2f a, b2, D, N, w0v, w1v, rD;                                     \
        a.x  = A0.x * K4.x; a.y  = A1.x * K4.x;                            \
        b2.x = A0.y * K4.y; b2.y = A1.y * K4.y;                            \
        D = (one + a) * (one + b2);                                        \
        N.x = wa.z; N.y = wa.z;                                            \
        w0v.x = wa.x; w0v.y = wa.x;                                        \
        w1v.x = wa.y; w1v.y = wa.y;                                        \
        N += w0v * b2; N += w1v * a;                                       \
        rD.x = __builtin_amdgcn_rcpf(D.x);                                 \
        rD.y = __builtin_amdgcn_rcpf(D.y);                                 \
        ACC += N * rD;                                                     \
        a.x  = A0.z * K4.z; a.y  = A1.z * K4.z;                            \
        b2.x = A0.w * K4.w; b2.y = A1.w * K4.w;                            \
        D = (one + a) * (one + b2);                                        \
        N.x = wb.z; N.y = wb.z;                                            \
        w0v.x = wb.x; w0v.y = wb.x;                                        \
        w1v.x = wb.y; w1v.y = wb.y;                                        \
        N += w0v * b2; N += w1v * a;                                       \
        rD.x = __builtin_amdgcn_rcpf(D.x);                                 \
        rD.y = __builtin_amdgcn_rcpf(D.y);                                 \
        ACC += N * rD;                                                     \
      }
      FF_PAIRK(K0, acc0)
      FF_PAIRK(K1, acc1)
      FF_PAIRK(K2, acc2)
      FF_PAIRK(K3, acc3)
#undef FF_PAIRK
    }
  }

  /* partials -> LDS (stride-5: lane-stride 20B, conflict-light) */
  {
    float* p = &pstp[(size_t)(hs * NK + k0) * 5 + 2 * rh];
    p[0] = acc0.x; p[1] = acc0.y;
    p[5] = acc1.x; p[6] = acc1.y;
    p[10] = acc2.x; p[11] = acc2.y;
    p[15] = acc3.x; p[16] = acc3.y;
  }
  __syncthreads();

  /* combine h-halves, E = exp2, Eg write, row sums */
  {
    const int k = t;                      /* 0..1023 */
    const float* p0 = &pstp[(size_t)k * 5];
    const float* p1 = &pstp[(size_t)(NK + k) * 5];
    const bool okm = k < vl;
    float e0 = okm ? __builtin_amdgcn_exp2f((p0[0] + p1[0]) * L2E) : 0.f;
    float e1 = okm ? __builtin_amdgcn_exp2f((p0[1] + p1[1]) * L2E) : 0.f;
    float e2 = okm ? __builtin_amdgcn_exp2f((p0[2] + p1[2]) * L2E) : 0.f;
    float e3 = okm ? __builtin_amdgcn_exp2f((p0[3] + p1[3]) * L2E) : 0.f;
    ((float4*)Eg)[((size_t)b * 64 + q4) * NK + k] = make_float4(e0, e1, e2, e3);
    float s0 = e0, s1 = e1, s2 = e2, s3 = e3;
    for (int o = 32; o; o >>= 1) {
      s0 += __shfl_xor(s0, o); s1 += __shfl_xor(s1, o);
      s2 += __shfl_xor(s2, o); s3 += __shfl_xor(s3, o);
    }
    if ((t & 63) == 0)
      *(float4*)&psum[(t >> 6) * 4] = make_float4(s0, s1, s2, s3);
  }
  __syncthreads();
  if (t < 4) {
    float S = 0.f;
    #pragma unroll
    for (int w = 0; w < 16; ++w) S += psum[w * 4 + t];
    Sg[(((size_t)b * 64 + q4)) * 4 + t] = S;
  }
}

/* PV kernel: grid (8 c-tiles, 64 q4, 4 b) = 2048 blocks x 256 thr, 8KB LDS
 * (~8 blk/CU).  Thread: cl=t&31 (c-pair), kq=t>>5 (128-k slice).  E read
 * via wave-uniform s_load (SMEM pipe); V b64 coalesced; 1/S at the end. */
__global__ __launch_bounds__(256) void ff_pv(
    const float* __restrict__ vals, const float* __restrict__ Eg,
    const float* __restrict__ Sg, const int* __restrict__ vlraw,
    float* __restrict__ out)
{
  __shared__ float part[8 * 4 * 64];      /* [kq][row][c-in-tile]   8 KB */
  const int t  = threadIdx.x;
  const int ct = blockIdx.x;              /* c-tile 0..7 */
  const int q4 = blockIdx.y;
  const int b  = blockIdx.z;

  int vls[4];
  ff_vldec(vlraw, vls);
  const int vl = vls[b];

  const int cl = t & 31, kq = t >> 5;
  const int c  = ct * 64 + cl * 2;
  const int k0 = kq * 128;
  int klen = vl - k0; klen = klen < 0 ? 0 : (klen > 128 ? 128 : klen);

  const float*  vb = vals + (size_t)b * NK * ND + (size_t)k0 * ND + c;
  const float4* ep = (const float4*)Eg + ((size_t)b * 64 + q4) * NK + k0;

  v2f a0 = {0.f,0.f}, a1 = {0.f,0.f}, a2 = {0.f,0.f}, a3 = {0.f,0.f};
  #pragma unroll 4
  for (int k = 0; k < klen; ++k) {
    float4 E = ep[k];                     /* uniform -> s_load */
    v2f v = *(const v2f*)(vb + (size_t)k * ND);
    v2f e;
    e.x = E.x; e.y = E.x; a0 += e * v;
    e.x = E.y; e.y = E.y; a1 += e * v;
    e.x = E.z; e.y = E.z; a2 += e * v;
    e.x = E.w; e.y = E.w; a3 += e * v;
  }
  {
    float* pp = &part[(size_t)(kq * 4) * 64 + cl * 2];
    *(v2f*)(pp      ) = a0;
    *(v2f*)(pp + 64 ) = a1;
    *(v2f*)(pp + 128) = a2;
    *(v2f*)(pp + 192) = a3;
  }
  __syncthreads();
  {
    const int r = t >> 6, cc = t & 63;
    float s = 0.f;
    #pragma unroll
    for (int q = 0; q < 8; ++q) s += part[(size_t)(q * 4 + r) * 64 + cc];
    const float S = Sg[(((size_t)b * 64 + q4)) * 4 + r];
    out[((size_t)b * NQ + q4 * QROWS + r) * ND + ct * 64 + cc] = s / S;
  }
}

/* Fallback attn (kp4 inputs, full K, in-kernel max-softmax) for small ws. */
__global__ __launch_bounds__(1024) void ff_attn(
    const float* __restrict__ qp, const float* __restrict__ kp,
    const float* __restrict__ vals, const int* __restrict__ vlraw,
    const float* __restrict__ wvp, float* __restrict__ out)
{
  __shared__ float qs[QROWS * NH];        /* [row][h] */
  __shared__ float ws[NH];
  __shared__ float st[NK * QROWS];
  __shared__ float pm[16], psm[16];
  __shared__ float part[4 * QROWS * ND];

  const int t  = threadIdx.x;
  const int q0 = blockIdx.x * QROWS;
  const int b  = blockIdx.y;

  {
    const float* qsrc = qp + ((size_t)b * NQ + q0) * NH;
    qs[t] = qsrc[t];
    if (t < NH) ws[t] = -2.0f * wvp[t];
  }
  __syncthreads();

  int vls[4];
  ff_vldec(vlraw, vls);
  const int vl = vls[b];

  float sc[4] = {0.f, 0.f, 0.f, 0.f};
  {
    const float4* kvp = (const float4*)kp + ((size_t)b * 64) * 1024 + t;
    for (int j = 0; j < 64; ++j) {
      float4 K4 = kvp[(size_t)j << 10];
      const float* wj = &ws[4 * j];
      #pragma unroll
      for (int r = 0; r < 4; ++r) {
        const float* qr = &qs[r * NH + 4 * j];
        sc[r] += wj[0] * __builtin_amdgcn_rcpf(1.0f + qr[0] * K4.x);
        sc[r] += wj[1] * __builtin_amdgcn_rcpf(1.0f + qr[1] * K4.y);
        sc[r] += wj[2] * __builtin_amdgcn_rcpf(1.0f + qr[2] * K4.z);
        sc[r] += wj[3] * __builtin_amdgcn_rcpf(1.0f + qr[3] * K4.w);
      }
    }
  }
  {
    const bool okm = (t < vl);
    *(float4*)&st[t * 4] = make_float4(okm ? sc[0] : -1e6f, okm ? sc[1] : -1e6f,
                                       okm ? sc[2] : -1e6f, okm ? sc[3] : -1e6f);
  }
  __syncthreads();

  {
    const int wid = t >> 6, lane = t & 63;
    const int row = wid >> 2, seg = wid & 3;
    const int kb = seg * 256 + lane;
    float v0 = st[(kb      ) * 4 + row];
    float v1 = st[(kb +  64) * 4 + row];
    float v2 = st[(kb + 128) * 4 + row];
    float v3 = st[(kb + 192) * 4 + row];
    float m = fmaxf(fmaxf(v0, v1), fmaxf(v2, v3));
    for (int o = 32; o; o >>= 1) m = fmaxf(m, __shfl_xor(m, o));
    if (lane == 0) pm[wid] = m;
    __syncthreads();
    m = fmaxf(fmaxf(pm[row*4+0], pm[row*4+1]), fmaxf(pm[row*4+2], pm[row*4+3]));
    float e0 = __builtin_amdgcn_exp2f((v0 - m) * L2E);
    float e1 = __builtin_amdgcn_exp2f((v1 - m) * L2E);
    float e2 = __builtin_amdgcn_exp2f((v2 - m) * L2E);
    float e3 = __builtin_amdgcn_exp2f((v3 - m) * L2E);
    float sm = e0 + e1 + e2 + e3;
    for (int o = 32; o; o >>= 1) sm += __shfl_xor(sm, o);
    if (lane == 0) psm[wid] = sm;
    __syncthreads();
    const float S = psm[row*4+0] + psm[row*4+1] + psm[row*4+2] + psm[row*4+3];
    const float rr = 1.0f / S;
    st[(kb      ) * 4 + row] = e0 * rr;
    st[(kb +  64) * 4 + row] = e1 * rr;
    st[(kb + 128) * 4 + row] = e2 * rr;
    st[(kb + 192) * 4 + row] = e3 * rr;
  }
  __syncthreads();

  {
    const int kq = t >> 8, c2 = (t & 255) * 2;
    const float* vb = vals + (size_t)b * NK * ND + c2;
    v2f o0 = {0.f,0.f}, o1 = {0.f,0.f}, o2 = {0.f,0.f}, o3 = {0.f,0.f};
    const int k0 = kq * 256;
    #pragma unroll 8
    for (int k = k0; k < k0 + 256; ++k) {
      v2f vv = *(const v2f*)(vb + (size_t)k * ND);
      float4 a = *(const float4*)&st[k * 4];
      v2f ax; ax.x = a.x; ax.y = a.x;
      v2f ay; ay.x = a.y; ay.y = a.y;
      v2f az; az.x = a.z; az.y = a.z;
      v2f aw; aw.x = a.w; aw.y = a.w;
      o0 += ax * vv; o1 += ay * vv; o2 += az * vv; o3 += aw * vv;
    }
    float* pp = &part[(size_t)kq * QROWS * ND + c2];
    *(v2f*)(pp         ) = o0;
    *(v2f*)(pp +     ND) = o1;
    *(v2f*)(pp + 2 * ND) = o2;
    *(v2f*)(pp + 3 * ND) = o3;
  }
  __syncthreads();
  {
    const int r = t >> 8, c2 = (t & 255) * 2;
    const float* pp = &part[(size_t)r * ND + c2];
    v2f s = {0.f, 0.f};
    #pragma unroll
    for (int kq = 0; kq < 4; ++kq) s += *(const v2f*)(pp + (size_t)kq * QROWS * ND);
    *(v2f*)(out + ((size_t)b * NQ + q0 + r) * ND + c2) = s;
  }
}

extern "C" void kernel_launch(void* const* d_in, const int* in_sizes, int n_in,
                              void* d_out, int out_size, void* d_ws, size_t ws_size,
                              hipStream_t stream) {
  const float* queries = (const float*)d_in[0];
  const float* keys    = (const float*)d_in[1];
  const float* values  = (const float*)d_in[2];
  const int*   vlens   = (const int*)d_in[3];
  const float* Wq      = (const float*)d_in[4];
  const float* Wk      = (const float*)d_in[5];
  const float* wv      = (const float*)d_in[6];
  float* out = (float*)d_out;               /* F32 OUTPUT */

  float* qp  = (float*)d_ws;                    /* 1 MB  */
  float* kp  = qp  + (size_t)NB * NQ * NH;      /* 4 MB (kp4 layout) */
  float* wtq = kp  + (size_t)NB * NH * NK;      /* 512 KB */
  float* wtk = wtq + (size_t)(ND / 4) * NH * 4; /* 512 KB */
  float* Eg  = wtk + (size_t)(ND / 4) * NH * 4; /* 4 MB (E float4/k) */
  float* Sg  = Eg  + (size_t)NB * 64 * NK * 4;  /* 4 KB  */
  const size_t need = ((size_t)(Sg - (float*)d_ws) + NB * 64 * 4) * sizeof(float);

  ff_wt  <<<dim3(128, 2), 256, 0, stream>>>(Wq, Wk, wtq, wtk);
  ff_proj<<<dim3((NB * (NQ + NK) / PJR) * (NH / PJH)), 256, 0, stream>>>(
      queries, keys, wtq, wtk, qp, kp);
  if (ws_size >= need) {
    ff_attn_s<<<dim3(NQ / QROWS, NB), 1024, 0, stream>>>(
        qp, kp, vlens, wv, Eg, Sg);
    ff_pv<<<dim3(8, NQ / QROWS, NB), 256, 0, stream>>>(
        values, Eg, Sg, vlens, out);
  } else {
    ff_attn<<<dim3(NQ / QROWS, NB), 1024, 0, stream>>>(
        qp, kp, values, vlens, wv, out);
  }
}

// Round 14
// 174.705 us; speedup vs baseline: 1.0820x; 1.0136x over previous
//
#include <hip/hip_runtime.h>
#include <stdint.h>

/* AdditiveAttention (B=4, Q=256, K=1024, D=512, H=256)
 * out[b,i,v] = sum_j softmax_j(sum_h tanh(q[b,i,h]+k[b,j,h])*wv[h]) * values[b,j,v],
 * masked to j < valid_lens[b].  OUTPUT IS FLOAT32 (R20 finding).
 *
 * R34: attn_s occupancy x2. R13's 49us: VALU 23us, LDS ~10us, kp-L2 ~4us ->
 * ~26us latency gap at 1 block/CU (grid 256, 4 waves/SIMD). Fix: kh=2 split
 * (grid 512) + pstp (40KB) replaced by lane-mapped hs-butterfly: h-quarter
 * index in lane bits 4-5 -> partials combined with 2 shfl_xor (16,32), no
 * big LDS, no barrier. LDS ~14KB; __launch_bounds__(1024,8) caps VGPR 64 ->
 * 2 blocks/CU = 8 waves/SIMD. Eg kept float4-per-k via 8KB el transpose
 * (rh=0/1 wave halves merged); Sg gains kh dim, ff_pv sums both halves.
 * FF_PAIRK math = R13-verified. proj/wt/pv else unchanged. */

#define NB 4
#define NQ 256
#define NK 1024
#define ND 512
#define NH 256
#define QROWS 4
#define PJR 16
#define PJH 64

#define C2L2E 2.8853900817779268f   /* 2*log2(e) */
#define L2E   1.4426950408889634f   /* log2(e)   */

typedef float v2f __attribute__((ext_vector_type(2)));

/* 8-class valid_lens decode: {i32,i64,f32,f64,i16,f16,bf16,fallback}. */
__device__ void ff_vldec(const int* p, int* v) {
  bool ok = true;
  for (int i = 0; i < 4; ++i) { int x = p[i]; if (x < 1 || x > NK) ok = false; }
  if (ok) { for (int i = 0; i < 4; ++i) v[i] = p[i]; return; }
  ok = true;
  for (int i = 0; i < 4; ++i) {
    if (p[2 * i + 1] != 0) ok = false;
    int x = p[2 * i]; if (x < 1 || x > NK) ok = false;
  }
  if (ok) { for (int i = 0; i < 4; ++i) v[i] = p[2 * i]; return; }
  ok = true;
  for (int i = 0; i < 4; ++i) {
    union { int i; float f; } u; u.i = p[i];
    if (!(u.f >= 1.0f && u.f <= 1024.0f && u.f == floorf(u.f))) ok = false;
  }
  if (ok) {
    for (int i = 0; i < 4; ++i) { union { int i; float f; } u; u.i = p[i]; v[i] = (int)u.f; }
    return;
  }
  ok = true;
  for (int i = 0; i < 4; ++i) {
    union { long long l; double d; } u;
    u.l = ((long long)p[2 * i + 1] << 32) | (unsigned int)p[2 * i];
    if (!(u.d >= 1.0 && u.d <= 1024.0 && u.d == floor(u.d))) ok = false;
  }
  if (ok) {
    for (int i = 0; i < 4; ++i) {
      union { long long l; double d; } u;
      u.l = ((long long)p[2 * i + 1] << 32) | (unsigned int)p[2 * i];
      v[i] = (int)u.d;
    }
    return;
  }
  const uint16_t* hh = (const uint16_t*)p;
  const short*    s  = (const short*)p;
  ok = true;
  for (int i = 0; i < 4; ++i) { int x = s[i]; if (x < 1 || x > NK) ok = false; }
  if (ok) { for (int i = 0; i < 4; ++i) v[i] = s[i]; return; }
  ok = true;
  for (int i = 0; i < 4; ++i) {
    union { uint16_t u; _Float16 h; } u; u.u = hh[i];
    float f = (float)u.h;
    if (!(f >= 1.0f && f <= 1024.0f && f == floorf(f))) ok = false;
  }
  if (ok) {
    for (int i = 0; i < 4; ++i) {
      union { uint16_t u; _Float16 h; } u; u.u = hh[i];
      v[i] = (int)(float)u.h;
    }
    return;
  }
  ok = true;
  for (int i = 0; i < 4; ++i) {
    union { uint32_t u; float f; } u; u.u = ((uint32_t)hh[i]) << 16;
    if (!(u.f >= 1.0f && u.f <= 1028.0f)) ok = false;
  }
  if (ok) {
    for (int i = 0; i < 4; ++i) {
      union { uint32_t u; float f; } u; u.u = ((uint32_t)hh[i]) << 16;
      int x = (int)(u.f + 0.5f); if (x > NK) x = NK; v[i] = x;
    }
    return;
  }
  for (int i = 0; i < 4; ++i) v[i] = NK;  /* fail-safe: unmasked */
}

/* Transpose W[h][d] -> WT float4 #(d4*NH+h) = C2L2E * W[h][4d4..4d4+3]. */
__global__ __launch_bounds__(256) void ff_wt(
    const float* __restrict__ Wq, const float* __restrict__ Wk,
    float* __restrict__ WTq, float* __restrict__ WTk)
{
  const int idx = blockIdx.x * 256 + threadIdx.x;   /* 0..32767 */
  const int d4 = idx & 127, h = idx >> 7;
  const float* src = blockIdx.y ? Wk : Wq;
  float*       dst = blockIdx.y ? WTk : WTq;
  float4 w = *(const float4*)(src + (size_t)h * ND + d4 * 4);
  w.x *= C2L2E; w.y *= C2L2E; w.z *= C2L2E; w.w *= C2L2E;
  *(float4*)(dst + ((size_t)d4 * NH + h) * 4) = w;
}

/* Projection (R11, proven): Aq=2^{q'} (qp [r][h]); Ak=2^{k'} interleaved
 * kp4[b][j][k] (float4 = h 4j..4j+3 at one k) via 4KB LDS transpose. */
__global__ __launch_bounds__(256) void ff_proj(
    const float* __restrict__ q_in, const float* __restrict__ k_in,
    const float* __restrict__ WTq, const float* __restrict__ WTk,
    float* __restrict__ qp, float* __restrict__ kp)
{
  __shared__ float xs[PJR * ND];                 /* 32 KB */
  const int t  = threadIdx.x;
  const int rg = blockIdx.x >> 2;                /* 0..319 */
  const int h0 = (blockIdx.x & 3) * PJH;
  const int gr0 = rg * PJR;
  const bool isq = gr0 < NB * NQ;
  const float* xin = isq ? (q_in + (size_t)gr0 * ND)
                         : (k_in + (size_t)(gr0 - NB * NQ) * ND);
  const float4* wt4 = (const float4*)(isq ? WTq : WTk);

  #pragma unroll
  for (int i = 0; i < 8; ++i)
    ((float4*)xs)[t + 256 * i] = ((const float4*)xin)[t + 256 * i];
  __syncthreads();

  const int L  = t & 63;
  const int rw = t >> 6;
  float a0 = 0.f, a1 = 0.f, a2 = 0.f, a3 = 0.f;
  const float4* xr = (const float4*)xs + (size_t)(4 * rw) * 128;

  #pragma unroll 4
  for (int d4 = 0; d4 < ND / 4; ++d4) {
    float4 w  = wt4[(size_t)d4 * NH + h0 + L];
    float4 x0 = xr[d4];
    float4 x1 = xr[128 + d4];
    float4 x2 = xr[256 + d4];
    float4 x3 = xr[384 + d4];
    a0 += w.x*x0.x + w.y*x0.y + w.z*x0.z + w.w*x0.w;
    a1 += w.x*x1.x + w.y*x1.y + w.z*x1.z + w.w*x1.w;
    a2 += w.x*x2.x + w.y*x2.y + w.z*x2.z + w.w*x2.w;
    a3 += w.x*x3.x + w.y*x3.y + w.z*x3.z + w.w*x3.w;
  }
  a0 = __builtin_amdgcn_exp2f(a0);
  a1 = __builtin_amdgcn_exp2f(a1);
  a2 = __builtin_amdgcn_exp2f(a2);
  a3 = __builtin_amdgcn_exp2f(a3);

  if (isq) {
    const int h = h0 + L;
    float* o = qp + (size_t)(gr0 + 4 * rw) * NH + h;
    o[0] = a0; o[NH] = a1; o[2 * NH] = a2; o[3 * NH] = a3;
  } else {
    __syncthreads();                         /* xs reads done */
    float* trs = xs;                         /* [64 h][16 k] */
    *(float4*)&trs[L * 16 + 4 * rw] = make_float4(a0, a1, a2, a3);
    __syncthreads();
    const int kl = t & 15, jl = t >> 4;      /* jl 0..15 */
    const int g0 = gr0 - NB * NQ;
    const int bb = g0 >> 10, kg0 = g0 & (NK - 1);
    const int j0 = (blockIdx.x & 3) * 16;
    float4 o4 = make_float4(trs[(4*jl+0)*16 + kl], trs[(4*jl+1)*16 + kl],
                            trs[(4*jl+2)*16 + kl], trs[(4*jl+3)*16 + kl]);
    ((float4*)kp)[((size_t)bb * 64 + j0 + jl) * 1024 + kg0 + kl] = o4;
  }
}

/* Scores kernel: grid (2 kh, 64 q4, 4 b) = 512 blocks, 1024 thr,
 * __launch_bounds__(1024,8) -> VGPR<=64 -> 2 blocks/CU (8 waves/SIMD).
 * Lane map: l = hs*16 + kl (hs = h-quarter in lane bits 4-5); wave
 * w = rh*8 + kw.  Thread: k = kh*512 + (kw*16+kl)*4 + [0,4), rows
 * {2rh,2rh+1}, j in [hs*16, hs*16+16).  Partials combined across hs via
 * shfl_xor(16),(32) — no pstp LDS.  E -> el (8KB) transpose -> Eg float4/k;
 * row-sums -> Sg[..][kh].  FF_PAIRK = R13-verified. */
__global__ __launch_bounds__(1024, 8) void ff_attn_s(
    const float* __restrict__ qp, const float* __restrict__ kp,
    const int* __restrict__ vlraw, const float* __restrict__ wvp,
    float* __restrict__ Eg, float* __restrict__ Sg)
{
  __shared__ float  qs[QROWS * NH];       /* Aq [row][h]            4 KB */
  __shared__ float4 wspp[NH / 2];         /* (-2w0,-2w1,-2(w0+w1),0) 2 KB */
  __shared__ float  el[512 * 4];          /* [k_local][row] E       8 KB */
  __shared__ float  psum[32];             /* [wave][2 rows]               */

  const int t  = threadIdx.x;
  const int kh = blockIdx.x;              /* k half 0..1 */
  const int q4 = blockIdx.y;
  const int b  = blockIdx.z;

  qs[t] = qp[((size_t)b * NQ + q4 * QROWS) * NH + t];
  if (t < NH / 2) {
    float w0 = wvp[2 * t], w1 = wvp[2 * t + 1];
    wspp[t] = make_float4(-2.0f * w0, -2.0f * w1, -2.0f * (w0 + w1), 0.0f);
  }
  __syncthreads();

  int vls[4];
  ff_vldec(vlraw, vls);
  const int vl = vls[b];

  const int l  = t & 63, w = t >> 6;
  const int hs = l >> 4, kl = l & 15;     /* h-quarter in lane bits 4-5 */
  const int kw = w & 7,  rh = w >> 3;
  const int kk = kw * 16 + kl;            /* 0..127 */
  const int k0 = kh * 512 + kk * 4;       /* global k base */

  v2f acc0 = {0.f,0.f}, acc1 = {0.f,0.f}, acc2 = {0.f,0.f}, acc3 = {0.f,0.f};
  {
    const float4* kvp = (const float4*)kp + (size_t)b * 64 * 1024 + k0;
    const float* q0p = qs + (2 * rh) * NH;
    const float* q1p = qs + (2 * rh + 1) * NH;

    for (int jj = 0; jj < 16; ++jj) {
      const int j = hs * 16 + jj;
      const float4* kj = kvp + ((size_t)j << 10);
      float4 K0 = kj[0], K1 = kj[1], K2 = kj[2], K3 = kj[3];
      float4 A0 = *(const float4*)(q0p + 4 * j);
      float4 A1 = *(const float4*)(q1p + 4 * j);
      float4 wa = wspp[2 * j];
      float4 wb = wspp[2 * j + 1];
      v2f one; one.x = 1.0f; one.y = 1.0f;

#define FF_PAIRK(K4, ACC)                                                  \
      {                                                                    \
        v2f a, b2, D, N, w0v, w1v, rD;                                     \
        a.x  = A0.x * K4.x; a.y  = A1.x * K4.x;                            \
        b2.x = A0.y * K4.y; b2.y = A1.y * K4.y;                            \
        D = (one + a) * (one + b2);                                        \
        N.x = wa.z; N.y = wa.z;                                            \
        w0v.x = wa.x; w0v.y = wa.x;                                        \
        w1v.x = wa.y; w1v.y = wa.y;                                        \
        N += w0v * b2; N += w1v * a;                                       \
        rD.x = __builtin_amdgcn_rcpf(D.x);                                 \
        rD.y = __builtin_amdgcn_rcpf(D.y);                                 \
        ACC += N * rD;                                                     \
        a.x  = A0.z * K4.z; a.y  = A1.z * K4.z;                            \
        b2.x = A0.w * K4.w; b2.y = A1.w * K4.w;                            \
        D = (one + a) * (one + b2);                                        \
        N.x = wb.z; N.y = wb.z;                                            \
        w0v.x = wb.x; w0v.y = wb.x;                                        \
        w1v.x = wb.y; w1v.y = wb.y;                                        \
        N += w0v * b2; N += w1v * a;                                       \
        rD.x = __builtin_amdgcn_rcpf(D.x);                                 \
        rD.y = __builtin_amdgcn_rcpf(D.y);                                 \
        ACC += N * rD;                                                     \
      }
      FF_PAIRK(K0, acc0)
      FF_PAIRK(K1, acc1)
      FF_PAIRK(K2, acc2)
      FF_PAIRK(K3, acc3)
#undef FF_PAIRK
    }
  }

  /* combine h-quarters across lanes l^16, l^32 (butterfly) */
#define FF_RED(v)                                                          \
  v.x += __shfl_xor(v.x, 16); v.x += __shfl_xor(v.x, 32);                  \
  v.y += __shfl_xor(v.y, 16); v.y += __shfl_xor(v.y, 32);
  FF_RED(acc0) FF_RED(acc1) FF_RED(acc2) FF_RED(acc3)
#undef FF_RED

  /* E = exp2(score'), masked -> 0 */
  float ex0, ey0, ex1, ey1, ex2, ey2, ex3, ey3;
  {
    const bool m0 = (k0 + 0) < vl, m1 = (k0 + 1) < vl;
    const bool m2 = (k0 + 2) < vl, m3 = (k0 + 3) < vl;
    ex0 = m0 ? __builtin_amdgcn_exp2f(acc0.x * L2E) : 0.f;
    ey0 = m0 ? __builtin_amdgcn_exp2f(acc0.y * L2E) : 0.f;
    ex1 = m1 ? __builtin_amdgcn_exp2f(acc1.x * L2E) : 0.f;
    ey1 = m1 ? __builtin_amdgcn_exp2f(acc1.y * L2E) : 0.f;
    ex2 = m2 ? __builtin_amdgcn_exp2f(acc2.x * L2E) : 0.f;
    ey2 = m2 ? __builtin_amdgcn_exp2f(acc2.y * L2E) : 0.f;
    ex3 = m3 ? __builtin_amdgcn_exp2f(acc3.x * L2E) : 0.f;
    ey3 = m3 ? __builtin_amdgcn_exp2f(acc3.y * L2E) : 0.f;
  }

  /* hs==0 lanes: stage E into el + contribute to row sums */
  if (hs == 0) {
    const int klc = kk * 4;
    el[(klc + 0) * 4 + 2 * rh] = ex0; el[(klc + 0) * 4 + 2 * rh + 1] = ey0;
    el[(klc + 1) * 4 + 2 * rh] = ex1; el[(klc + 1) * 4 + 2 * rh + 1] = ey1;
    el[(klc + 2) * 4 + 2 * rh] = ex2; el[(klc + 2) * 4 + 2 * rh + 1] = ey2;
    el[(klc + 3) * 4 + 2 * rh] = ex3; el[(klc + 3) * 4 + 2 * rh + 1] = ey3;
  }
  {
    float sl = (hs == 0) ? ((ex0 + ex1) + (ex2 + ex3)) : 0.f;
    float sh = (hs == 0) ? ((ey0 + ey1) + (ey2 + ey3)) : 0.f;
    for (int o = 32; o; o >>= 1) { sl += __shfl_xor(sl, o); sh += __shfl_xor(sh, o); }
    if (l == 0) { psum[w * 2] = sl; psum[w * 2 + 1] = sh; }
  }
  __syncthreads();

  /* Eg write (float4 per k, coalesced) */
  if (t < 512)
    ((float4*)Eg)[((size_t)b * 64 + q4) * NK + kh * 512 + t]
        = *(const float4*)&el[t * 4];

  if (t < 4) {                            /* row r: waves rh=r>>1, comp r&1 */
    const int c = t & 1, base = (t >> 1) * 8;
    float S = 0.f;
    #pragma unroll
    for (int kw2 = 0; kw2 < 8; ++kw2) S += psum[(base + kw2) * 2 + c];
    Sg[(((size_t)b * 64 + q4) * 4 + t) * 2 + kh] = S;
  }
}

/* PV kernel: grid (8 c-tiles, 64 q4, 4 b) = 2048 blocks x 256 thr, 8KB LDS.
 * Thread: cl=t&31 (c-pair), kq=t>>5 (128-k slice).  Sg summed over kh. */
__global__ __launch_bounds__(256) void ff_pv(
    const float* __restrict__ vals, const float* __restrict__ Eg,
    const float* __restrict__ Sg, const int* __restrict__ vlraw,
    float* __restrict__ out)
{
  __shared__ float part[8 * 4 * 64];      /* [kq][row][c-in-tile]   8 KB */
  const int t  = threadIdx.x;
  const int ct = blockIdx.x;              /* c-tile 0..7 */
  const int q4 = blockIdx.y;
  const int b  = blockIdx.z;

  int vls[4];
  ff_vldec(vlraw, vls);
  const int vl = vls[b];

  const int cl = t & 31, kq = t >> 5;
  const int c  = ct * 64 + cl * 2;
  const int k0 = kq * 128;
  int klen = vl - k0; klen = klen < 0 ? 0 : (klen > 128 ? 128 : klen);

  const float*  vb = vals + (size_t)b * NK * ND + (size_t)k0 * ND + c;
  const float4* ep = (const float4*)Eg + ((size_t)b * 64 + q4) * NK + k0;

  v2f a0 = {0.f,0.f}, a1 = {0.f,0.f}, a2 = {0.f,0.f}, a3 = {0.f,0.f};
  #pragma unroll 4
  for (int k = 0; k < klen; ++k) {
    float4 E = ep[k];
    v2f v = *(const v2f*)(vb + (size_t)k * ND);
    v2f e;
    e.x = E.x; e.y = E.x; a0 += e * v;
    e.x = E.y; e.y = E.y; a1 += e * v;
    e.x = E.z; e.y = E.z; a2 += e * v;
    e.x = E.w; e.y = E.w; a3 += e * v;
  }
  {
    float* pp = &part[(size_t)(kq * 4) * 64 + cl * 2];
    *(v2f*)(pp      ) = a0;
    *(v2f*)(pp + 64 ) = a1;
    *(v2f*)(pp + 128) = a2;
    *(v2f*)(pp + 192) = a3;
  }
  __syncthreads();
  {
    const int r = t >> 6, cc = t & 63;
    float s = 0.f;
    #pragma unroll
    for (int q = 0; q < 8; ++q) s += part[(size_t)(q * 4 + r) * 64 + cc];
    const size_t sb = ((size_t)b * 64 + q4) * 4 + r;
    const float S = Sg[sb * 2] + Sg[sb * 2 + 1];
    out[((size_t)b * NQ + q4 * QROWS + r) * ND + ct * 64 + cc] = s / S;
  }
}

/* Fallback attn (kp4 inputs, full K, in-kernel max-softmax) for small ws. */
__global__ __launch_bounds__(1024) void ff_attn(
    const float* __restrict__ qp, const float* __restrict__ kp,
    const float* __restrict__ vals, const int* __restrict__ vlraw,
    const float* __restrict__ wvp, float* __restrict__ out)
{
  __shared__ float qs[QROWS * NH];        /* [row][h] */
  __shared__ float ws[NH];
  __shared__ float st[NK * QROWS];
  __shared__ float pm[16], psm[16];
  __shared__ float part[4 * QROWS * ND];

  const int t  = threadIdx.x;
  const int q0 = blockIdx.x * QROWS;
  const int b  = blockIdx.y;

  {
    const float* qsrc = qp + ((size_t)b * NQ + q0) * NH;
    qs[t] = qsrc[t];
    if (t < NH) ws[t] = -2.0f * wvp[t];
  }
  __syncthreads();

  int vls[4];
  ff_vldec(vlraw, vls);
  const int vl = vls[b];

  float sc[4] = {0.f, 0.f, 0.f, 0.f};
  {
    const float4* kvp = (const float4*)kp + ((size_t)b * 64) * 1024 + t;
    for (int j = 0; j < 64; ++j) {
      float4 K4 = kvp[(size_t)j << 10];
      const float* wj = &ws[4 * j];
      #pragma unroll
      for (int r = 0; r < 4; ++r) {
        const float* qr = &qs[r * NH + 4 * j];
        sc[r] += wj[0] * __builtin_amdgcn_rcpf(1.0f + qr[0] * K4.x);
        sc[r] += wj[1] * __builtin_amdgcn_rcpf(1.0f + qr[1] * K4.y);
        sc[r] += wj[2] * __builtin_amdgcn_rcpf(1.0f + qr[2] * K4.z);
        sc[r] += wj[3] * __builtin_amdgcn_rcpf(1.0f + qr[3] * K4.w);
      }
    }
  }
  {
    const bool okm = (t < vl);
    *(float4*)&st[t * 4] = make_float4(okm ? sc[0] : -1e6f, okm ? sc[1] : -1e6f,
                                       okm ? sc[2] : -1e6f, okm ? sc[3] : -1e6f);
  }
  __syncthreads();

  {
    const int wid = t >> 6, lane = t & 63;
    const int row = wid >> 2, seg = wid & 3;
    const int kb = seg * 256 + lane;
    float v0 = st[(kb      ) * 4 + row];
    float v1 = st[(kb +  64) * 4 + row];
    float v2 = st[(kb + 128) * 4 + row];
    float v3 = st[(kb + 192) * 4 + row];
    float m = fmaxf(fmaxf(v0, v1), fmaxf(v2, v3));
    for (int o = 32; o; o >>= 1) m = fmaxf(m, __shfl_xor(m, o));
    if (lane == 0) pm[wid] = m;
    __syncthreads();
    m = fmaxf(fmaxf(pm[row*4+0], pm[row*4+1]), fmaxf(pm[row*4+2], pm[row*4+3]));
    float e0 = __builtin_amdgcn_exp2f((v0 - m) * L2E);
    float e1 = __builtin_amdgcn_exp2f((v1 - m) * L2E);
    float e2 = __builtin_amdgcn_exp2f((v2 - m) * L2E);
    float e3 = __builtin_amdgcn_exp2f((v3 - m) * L2E);
    float sm = e0 + e1 + e2 + e3;
    for (int o = 32; o; o >>= 1) sm += __shfl_xor(sm, o);
    if (lane == 0) psm[wid] = sm;
    __syncthreads();
    const float S = psm[row*4+0] + psm[row*4+1] + psm[row*4+2] + psm[row*4+3];
    const float rr = 1.0f / S;
    st[(kb      ) * 4 + row] = e0 * rr;
    st[(kb +  64) * 4 + row] = e1 * rr;
    st[(kb + 128) * 4 + row] = e2 * rr;
    st[(kb + 192) * 4 + row] = e3 * rr;
  }
  __syncthreads();

  {
    const int kq = t >> 8, c2 = (t & 255) * 2;
    const float* vb = vals + (size_t)b * NK * ND + c2;
    v2f o0 = {0.f,0.f}, o1 = {0.f,0.f}, o2 = {0.f,0.f}, o3 = {0.f,0.f};
    const int k0 = kq * 256;
    #pragma unroll 8
    for (int k = k0; k < k0 + 256; ++k) {
      v2f vv = *(const v2f*)(vb + (size_t)k * ND);
      float4 a = *(const float4*)&st[k * 4];
      v2f ax; ax.x = a.x; ax.y = a.x;
      v2f ay; ay.x = a.y; ay.y = a.y;
      v2f az; az.x = a.z; az.y = a.z;
      v2f aw; aw.x = a.w; aw.y = a.w;
      o0 += ax * vv; o1 += ay * vv; o2 += az * vv; o3 += aw * vv;
    }
    float* pp = &part[(size_t)kq * QROWS * ND + c2];
    *(v2f*)(pp         ) = o0;
    *(v2f*)(pp +     ND) = o1;
    *(v2f*)(pp + 2 * ND) = o2;
    *(v2f*)(pp + 3 * ND) = o3;
  }
  __syncthreads();
  {
    const int r = t >> 8, c2 = (t & 255) * 2;
    const float* pp = &part[(size_t)r * ND + c2];
    v2f s = {0.f, 0.f};
    #pragma unroll
    for (int kq = 0; kq < 4; ++kq) s += *(const v2f*)(pp + (size_t)kq * QROWS * ND);
    *(v2f*)(out + ((size_t)b * NQ + q0 + r) * ND + c2) = s;
  }
}

extern "C" void kernel_launch(void* const* d_in, const int* in_sizes, int n_in,
                              void* d_out, int out_size, void* d_ws, size_t ws_size,
                              hipStream_t stream) {
  const float* queries = (const float*)d_in[0];
  const float* keys    = (const float*)d_in[1];
  const float* values  = (const float*)d_in[2];
  const int*   vlens   = (const int*)d_in[3];
  const float* Wq      = (const float*)d_in[4];
  const float* Wk      = (const float*)d_in[5];
  const float* wv      = (const float*)d_in[6];
  float* out = (float*)d_out;               /* F32 OUTPUT */

  float* qp  = (float*)d_ws;                    /* 1 MB  */
  float* kp  = qp  + (size_t)NB * NQ * NH;      /* 4 MB (kp4 layout) */
  float* wtq = kp  + (size_t)NB * NH * NK;      /* 512 KB */
  float* wtk = wtq + (size_t)(ND / 4) * NH * 4; /* 512 KB */
  float* Eg  = wtk + (size_t)(ND / 4) * NH * 4; /* 4 MB (E float4/k) */
  float* Sg  = Eg  + (size_t)NB * 64 * NK * 4;  /* 8 KB (x2 kh) */
  const size_t need = ((size_t)(Sg - (float*)d_ws) + NB * 64 * 4 * 2) * sizeof(float);

  ff_wt  <<<dim3(128, 2), 256, 0, stream>>>(Wq, Wk, wtq, wtk);
  ff_proj<<<dim3((NB * (NQ + NK) / PJR) * (NH / PJH)), 256, 0, stream>>>(
      queries, keys, wtq, wtk, qp, kp);
  if (ws_size >= need) {
    ff_attn_s<<<dim3(2, NQ / QROWS, NB), 1024, 0, stream>>>(
        qp, kp, vlens, wv, Eg, Sg);
    ff_pv<<<dim3(8, NQ / QROWS, NB), 256, 0, stream>>>(
        values, Eg, Sg, vlens, out);
  } else {
    ff_attn<<<dim3(NQ / QROWS, NB), 1024, 0, stream>>>(
        qp, kp, values, vlens, wv, out);
  }
}